// Round 3
// baseline (561.514 us; speedup 1.0000x reference)
//
#include <hip/hip_runtime.h>
#include <math.h>

#define IN_DIM 128
#define NH 8
#define OC 16
#define HC 128   // NH*OC
#define CHUNK 128
#define BSTR 136 // padded bf16 stride for LDS B tiles: 272B row => 16B-aligned b128 reads,
                 // bank start 4c%32 -> 2-way aliasing (free per m136)

typedef __attribute__((ext_vector_type(8))) short short8;
typedef __attribute__((ext_vector_type(4))) float f32x4;

__device__ __forceinline__ unsigned short bf16_rne(float f) {
  unsigned int u = __builtin_bit_cast(unsigned int, f);
  u += 0x7FFFu + ((u >> 16) & 1u);
  return (unsigned short)(u >> 16);
}
__device__ __forceinline__ float bf16_to_f(unsigned short h) {
  unsigned int u = ((unsigned int)h) << 16;
  return __builtin_bit_cast(float, u);
}

// ---------------- K1: x = feature@w_lin, res(->d_out) = feature@w_res ----
// MFMA split-bf16 (A = Ah+Al, B = Bh+Bl; D = AhBh + AhBl + AlBh, rel err ~2^-15).
__global__ __launch_bounds__(256) void k1_mfma(const float* __restrict__ feature,
                                               const float* __restrict__ w_lin,
                                               const float* __restrict__ w_res,
                                               float* __restrict__ x,
                                               float* __restrict__ res,
                                               int N) {
  __shared__ unsigned short Bhi[256 * BSTR];  // 69.6 KB
  __shared__ unsigned short Blo[256 * BSTR];  // 69.6 KB
  const int t = threadIdx.x;

  {
    const int c = t;
    const float* __restrict__ Wp = (c < HC) ? (w_lin + c) : (w_res + (c - HC));
    for (int k0 = 0; k0 < IN_DIM; k0 += 4) {
      unsigned short h[4], l[4];
#pragma unroll
      for (int j = 0; j < 4; ++j) {
        const float f = Wp[(size_t)(k0 + j) * HC];
        h[j] = bf16_rne(f);
        l[j] = bf16_rne(f - bf16_to_f(h[j]));
      }
      *(ushort4*)&Bhi[c * BSTR + k0] = make_ushort4(h[0], h[1], h[2], h[3]);
      *(ushort4*)&Blo[c * BSTR + k0] = make_ushort4(l[0], l[1], l[2], l[3]);
    }
  }
  __syncthreads();

  const int wave = t >> 6, lane = t & 63;
  const int n16 = lane & 15;
  const int quad = lane >> 4;
  const int nStrips = (N + 15) >> 4;

  for (int strip = blockIdx.x * 4 + wave; strip < nStrips; strip += gridDim.x * 4) {
    const int row0 = strip * 16;
    const int arow = row0 + n16;
    const float* __restrict__ ap =
        feature + (size_t)((arow < N) ? arow : 0) * IN_DIM + quad * 8;

    short8 ahi[4], alo[4];
#pragma unroll
    for (int ks = 0; ks < 4; ++ks) {
      const float4 f0 = *(const float4*)(ap + ks * 32);
      const float4 f1 = *(const float4*)(ap + ks * 32 + 4);
      const float fv[8] = {f0.x, f0.y, f0.z, f0.w, f1.x, f1.y, f1.z, f1.w};
      short8 h, l;
#pragma unroll
      for (int j = 0; j < 8; ++j) {
        const unsigned short hh = bf16_rne(fv[j]);
        h[j] = (short)hh;
        l[j] = (short)bf16_rne(fv[j] - bf16_to_f(hh));
      }
      ahi[ks] = h;
      alo[ks] = l;
    }

#pragma unroll
    for (int cg = 0; cg < 4; ++cg) {
      f32x4 acc[4] = {{0.f, 0.f, 0.f, 0.f},
                      {0.f, 0.f, 0.f, 0.f},
                      {0.f, 0.f, 0.f, 0.f},
                      {0.f, 0.f, 0.f, 0.f}};
#pragma unroll
      for (int ks = 0; ks < 4; ++ks) {
#pragma unroll
        for (int j = 0; j < 4; ++j) {
          const int boff = ((cg * 4 + j) * 16 + n16) * BSTR + ks * 32 + quad * 8;
          const short8 bh = *(const short8*)&Bhi[boff];
          const short8 bl = *(const short8*)&Blo[boff];
          acc[j] = __builtin_amdgcn_mfma_f32_16x16x32_bf16(ahi[ks], bh, acc[j], 0, 0, 0);
          acc[j] = __builtin_amdgcn_mfma_f32_16x16x32_bf16(ahi[ks], bl, acc[j], 0, 0, 0);
          acc[j] = __builtin_amdgcn_mfma_f32_16x16x32_bf16(alo[ks], bh, acc[j], 0, 0, 0);
        }
      }
#pragma unroll
      for (int j = 0; j < 4; ++j) {
        const int ct = cg * 4 + j;
        float* __restrict__ dp = (ct < 8) ? x : res;
        const int colo = (ct & 7) * 16 + n16;
#pragma unroll
        for (int r = 0; r < 4; ++r) {
          const int rr = row0 + quad * 4 + r;
          if (rr < N) dp[(size_t)rr * HC + colo] = acc[j][r];
        }
      }
    }
  }
}

// ---------------- K1b: al[n,h] = <x[n,h,:], att_l[h,:]>, ar likewise ------
__global__ __launch_bounds__(256) void k1b_attn(const float* __restrict__ x,
                                                const float* __restrict__ att_l,
                                                const float* __restrict__ att_r,
                                                float* __restrict__ al,
                                                float* __restrict__ ar,
                                                int N) {
  const int idx = blockIdx.x * 256 + threadIdx.x;
  if (idx >= N * NH) return;
  const int h = idx & (NH - 1);
  const float4* xp = (const float4*)(x + (size_t)idx * OC);
  const float4* lp = (const float4*)(att_l + h * OC);
  const float4* rp = (const float4*)(att_r + h * OC);
  float sl = 0.f, sr = 0.f;
#pragma unroll
  for (int q = 0; q < 4; ++q) {
    const float4 xv = xp[q], lv = lp[q], rv = rp[q];
    sl += xv.x * lv.x + xv.y * lv.y + xv.z * lv.z + xv.w * lv.w;
    sr += xv.x * rv.x + xv.y * rv.y + xv.z * rv.z + xv.w * rv.w;
  }
  al[idx] = sl;
  ar[idx] = sr;
}

// ---------------- K2: histogram of edge destinations ---------------------
__global__ __launch_bounds__(256) void k2_count(const int* __restrict__ edst,
                                                int* __restrict__ count, int E) {
  const int e = blockIdx.x * 256 + threadIdx.x;
  if (e < E) atomicAdd(&count[edst[e]], 1);
}

// ---------------- K3: exclusive scan -> row_start + cursor ---------------
__global__ __launch_bounds__(1024) void k3_scan(const int* __restrict__ count,
                                                int* __restrict__ row_start,
                                                int* __restrict__ cursor, int N) {
  __shared__ int s[1024];
  const int t = threadIdx.x;
  const int CH = (N + 1023) / 1024;
  int lo = t * CH;
  if (lo > N) lo = N;
  int hi = lo + CH;
  if (hi > N) hi = N;
  int sum = 0;
  for (int i = lo; i < hi; ++i) sum += count[i];
  s[t] = sum;
  __syncthreads();
  for (int off = 1; off < 1024; off <<= 1) {
    const int add = (t >= off) ? s[t - off] : 0;
    __syncthreads();
    s[t] += add;
    __syncthreads();
  }
  int run = s[t] - sum;
  for (int i = lo; i < hi; ++i) {
    row_start[i] = run;
    cursor[i] = run;
    run += count[i];
  }
  if (t == 1023) row_start[N] = s[1023];
}

// ---------------- K4: scatter packed (src, weight) into CSR buckets ------
// 8B per edge instead of 36B; alpha is recomputed in k5 from L2-resident al.
__global__ __launch_bounds__(256) void k4_pack(const int* __restrict__ esrc,
                                               const int* __restrict__ edst,
                                               const float* __restrict__ ew,
                                               int* __restrict__ cursor,
                                               uint2* __restrict__ packed, int E) {
  const int e = blockIdx.x * 256 + threadIdx.x;
  if (e >= E) return;
  const int sN = esrc[e], dN = edst[e];
  const unsigned int wb = __float_as_uint(ew[e]);
  const int pos = atomicAdd(&cursor[dN], 1);
  packed[pos] = make_uint2((unsigned int)sN, wb);
}

// ---------------- K5: alpha recompute + softmax + gather-accum + elu -----
// Block = 128 threads = one dst node. Mapping A (h=t&7, i=t>>3) edge-wise;
// mapping B (h=t>>4, c=t&15) feature-wise. alpha_e,h =
// leakyrelu(w_e*(al[src_e,h]+ar[n,h])); ar[n] is a block constant.
__global__ __launch_bounds__(128) void k5_agg(const float* __restrict__ x,
                                              const uint2* __restrict__ packed,
                                              const int* __restrict__ row_start,
                                              const float* __restrict__ al,
                                              const float* __restrict__ ar,
                                              float* __restrict__ out, int N) {
  const int n = blockIdx.x;
  const int t = threadIdx.x;
  const int s0 = row_start[n];
  const int En = row_start[n + 1] - s0;
  __shared__ float red[128];
  __shared__ float mx[NH];
  __shared__ float inv8[NH];
  __shared__ float arn[NH];
  __shared__ float ebuf[CHUNK * NH];
  __shared__ float wbuf[CHUNK];
  __shared__ int sbuf[CHUNK];
  const int h_a = t & 7, i_a = t >> 3;
  if (t < NH) arn[t] = ar[(size_t)n * NH + t];
  __syncthreads();

  // ---- pass 1: per-head max; stash alpha in ebuf (valid iff En<=CHUNK) ---
  float lm = -INFINITY;
  for (int base = 0; base < En; base += CHUNK) {
    const int cnt = min(CHUNK, En - base);
    __syncthreads();
    for (int i = t; i < cnt; i += 128) {
      const uint2 p = packed[s0 + base + i];
      sbuf[i] = (int)p.x;
      wbuf[i] = __uint_as_float(p.y);
    }
    __syncthreads();
    for (int i = i_a; i < cnt; i += 16) {
      float a = wbuf[i] * (al[(size_t)sbuf[i] * NH + h_a] + arn[h_a]);
      a = (a > 0.f) ? a : 0.2f * a;
      ebuf[i * NH + h_a] = a;
      lm = fmaxf(lm, a);
    }
  }
  red[t] = lm;
  __syncthreads();
  if (t < NH) {
    float m = red[t];
    for (int j = 1; j < 16; ++j) m = fmaxf(m, red[j * NH + t]);
    mx[t] = m;
  }
  __syncthreads();

  const int h_b = t >> 4, c = t & 15;
  float dpart = 0.f, facc = 0.f;
  if (En <= CHUNK) {
    // ---- fast path: sbuf/wbuf/ebuf still hold the whole bucket ----
    for (int i = i_a; i < En; i += 16) {
      const float e = __expf(ebuf[i * NH + h_a] - mx[h_a]);
      ebuf[i * NH + h_a] = e;
      dpart += e;
    }
    __syncthreads();
    for (int i = 0; i < En; ++i) {
      facc = fmaf(ebuf[i * NH + h_b], x[(size_t)sbuf[i] * HC + h_b * OC + c], facc);
    }
  } else {
    // ---- fallback: re-stage chunks, recompute alpha ----
    for (int base = 0; base < En; base += CHUNK) {
      const int cnt = min(CHUNK, En - base);
      __syncthreads();
      for (int i = t; i < cnt; i += 128) {
        const uint2 p = packed[s0 + base + i];
        sbuf[i] = (int)p.x;
        wbuf[i] = __uint_as_float(p.y);
      }
      __syncthreads();
      for (int i = i_a; i < cnt; i += 16) {
        float a = wbuf[i] * (al[(size_t)sbuf[i] * NH + h_a] + arn[h_a]);
        a = (a > 0.f) ? a : 0.2f * a;
        const float e = __expf(a - mx[h_a]);
        ebuf[i * NH + h_a] = e;
        dpart += e;
      }
      __syncthreads();
      for (int i = 0; i < cnt; ++i) {
        facc = fmaf(ebuf[i * NH + h_b], x[(size_t)sbuf[i] * HC + h_b * OC + c], facc);
      }
    }
  }
  __syncthreads();

  red[t] = dpart;
  __syncthreads();
  if (t < NH) {
    float sden = 0.f;
    for (int j = 0; j < 16; ++j) sden += red[j * NH + t];
    inv8[t] = 1.f / sden;
  }
  __syncthreads();

  const float feat = (En > 0) ? facc * inv8[h_b] : 0.f;
  const float o = (feat > 0.f) ? feat : (__expf(feat) - 1.f);  // elu
  out[(size_t)n * HC + t] += o;  // out already holds the residual from k1
}

extern "C" void kernel_launch(void* const* d_in, const int* in_sizes, int n_in,
                              void* d_out, int out_size, void* d_ws, size_t ws_size,
                              hipStream_t stream) {
  const float* feature = (const float*)d_in[0];
  const int* esrc = (const int*)d_in[1];
  const int* edst = (const int*)d_in[2];
  const float* ew = (const float*)d_in[3];
  const float* w_lin = (const float*)d_in[4];
  const float* att_l = (const float*)d_in[5];
  const float* att_r = (const float*)d_in[6];
  const float* w_res = (const float*)d_in[7];
  float* out = (float*)d_out;

  const int N = in_sizes[0] / IN_DIM;
  const int E = in_sizes[1];

  char* ws = (char*)d_ws;
  size_t off = 0;
  auto alloc = [&](size_t bytes) {
    void* p = ws + off;
    off = (off + bytes + 255) & ~(size_t)255;
    return p;
  };
  float* x = (float*)alloc((size_t)N * HC * sizeof(float));
  float* al = (float*)alloc((size_t)N * NH * sizeof(float));
  float* ar = (float*)alloc((size_t)N * NH * sizeof(float));
  int* count = (int*)alloc((size_t)N * sizeof(int));
  int* row_start = (int*)alloc((size_t)(N + 1) * sizeof(int));
  int* cursor = (int*)alloc((size_t)N * sizeof(int));
  uint2* packed = (uint2*)alloc((size_t)E * sizeof(uint2));

  hipMemsetAsync(count, 0, (size_t)N * sizeof(int), stream);
  k1_mfma<<<256, 256, 0, stream>>>(feature, w_lin, w_res, x, out, N);
  k1b_attn<<<(N * NH + 255) / 256, 256, 0, stream>>>(x, att_l, att_r, al, ar, N);
  k2_count<<<(E + 255) / 256, 256, 0, stream>>>(edst, count, E);
  k3_scan<<<1, 1024, 0, stream>>>(count, row_start, cursor, N);
  k4_pack<<<(E + 255) / 256, 256, 0, stream>>>(esrc, edst, ew, cursor, packed, E);
  k5_agg<<<N, 128, 0, stream>>>(x, packed, row_start, al, ar, out, N);
}

// Round 4
// 429.280 us; speedup vs baseline: 1.3080x; 1.3080x over previous
//
#include <hip/hip_runtime.h>
#include <math.h>

#define IN_DIM 128
#define NH 8
#define OC 16
#define HC 128   // NH*OC
#define CHUNK 128
#define BSTR 136 // padded bf16 stride for LDS B tiles (2-way bank aliasing = free)
#define SCAN_BLOCKS 128  // 128 * 512 = 65536 >= N

typedef __attribute__((ext_vector_type(8))) short short8;
typedef __attribute__((ext_vector_type(4))) float f32x4;

__device__ __forceinline__ unsigned short bf16_rne(float f) {
  unsigned int u = __builtin_bit_cast(unsigned int, f);
  u += 0x7FFFu + ((u >> 16) & 1u);
  return (unsigned short)(u >> 16);
}
__device__ __forceinline__ float bf16_to_f(unsigned short h) {
  unsigned int u = ((unsigned int)h) << 16;
  return __builtin_bit_cast(float, u);
}

// ---------------- K1: x = feature@w_lin, res(->d_out) = feature@w_res ----
// MFMA split-bf16 (A = Ah+Al, B = Bh+Bl; D = AhBh + AhBl + AlBh, rel err ~2^-15).
__global__ __launch_bounds__(256) void k1_mfma(const float* __restrict__ feature,
                                               const float* __restrict__ w_lin,
                                               const float* __restrict__ w_res,
                                               float* __restrict__ x,
                                               float* __restrict__ res,
                                               int N) {
  __shared__ unsigned short Bhi[256 * BSTR];  // 69.6 KB
  __shared__ unsigned short Blo[256 * BSTR];  // 69.6 KB
  const int t = threadIdx.x;

  {
    const int c = t;
    const float* __restrict__ Wp = (c < HC) ? (w_lin + c) : (w_res + (c - HC));
    for (int k0 = 0; k0 < IN_DIM; k0 += 4) {
      unsigned short h[4], l[4];
#pragma unroll
      for (int j = 0; j < 4; ++j) {
        const float f = Wp[(size_t)(k0 + j) * HC];
        h[j] = bf16_rne(f);
        l[j] = bf16_rne(f - bf16_to_f(h[j]));
      }
      *(ushort4*)&Bhi[c * BSTR + k0] = make_ushort4(h[0], h[1], h[2], h[3]);
      *(ushort4*)&Blo[c * BSTR + k0] = make_ushort4(l[0], l[1], l[2], l[3]);
    }
  }
  __syncthreads();

  const int wave = t >> 6, lane = t & 63;
  const int n16 = lane & 15;
  const int quad = lane >> 4;
  const int nStrips = (N + 15) >> 4;

  for (int strip = blockIdx.x * 4 + wave; strip < nStrips; strip += gridDim.x * 4) {
    const int row0 = strip * 16;
    const int arow = row0 + n16;
    const float* __restrict__ ap =
        feature + (size_t)((arow < N) ? arow : 0) * IN_DIM + quad * 8;

    short8 ahi[4], alo[4];
#pragma unroll
    for (int ks = 0; ks < 4; ++ks) {
      const float4 f0 = *(const float4*)(ap + ks * 32);
      const float4 f1 = *(const float4*)(ap + ks * 32 + 4);
      const float fv[8] = {f0.x, f0.y, f0.z, f0.w, f1.x, f1.y, f1.z, f1.w};
      short8 h, l;
#pragma unroll
      for (int j = 0; j < 8; ++j) {
        const unsigned short hh = bf16_rne(fv[j]);
        h[j] = (short)hh;
        l[j] = (short)bf16_rne(fv[j] - bf16_to_f(hh));
      }
      ahi[ks] = h;
      alo[ks] = l;
    }

#pragma unroll
    for (int cg = 0; cg < 4; ++cg) {
      f32x4 acc[4] = {{0.f, 0.f, 0.f, 0.f},
                      {0.f, 0.f, 0.f, 0.f},
                      {0.f, 0.f, 0.f, 0.f},
                      {0.f, 0.f, 0.f, 0.f}};
#pragma unroll
      for (int ks = 0; ks < 4; ++ks) {
#pragma unroll
        for (int j = 0; j < 4; ++j) {
          const int boff = ((cg * 4 + j) * 16 + n16) * BSTR + ks * 32 + quad * 8;
          const short8 bh = *(const short8*)&Bhi[boff];
          const short8 bl = *(const short8*)&Blo[boff];
          acc[j] = __builtin_amdgcn_mfma_f32_16x16x32_bf16(ahi[ks], bh, acc[j], 0, 0, 0);
          acc[j] = __builtin_amdgcn_mfma_f32_16x16x32_bf16(ahi[ks], bl, acc[j], 0, 0, 0);
          acc[j] = __builtin_amdgcn_mfma_f32_16x16x32_bf16(alo[ks], bh, acc[j], 0, 0, 0);
        }
      }
#pragma unroll
      for (int j = 0; j < 4; ++j) {
        const int ct = cg * 4 + j;
        float* __restrict__ dp = (ct < 8) ? x : res;
        const int colo = (ct & 7) * 16 + n16;
#pragma unroll
        for (int r = 0; r < 4; ++r) {
          const int rr = row0 + quad * 4 + r;
          if (rr < N) dp[(size_t)rr * HC + colo] = acc[j][r];
        }
      }
    }
  }
}

// ---------------- K1b: al/ar logits + bf16 copy of x for the k5 gather ---
__global__ __launch_bounds__(256) void k1b_attn(const float* __restrict__ x,
                                                const float* __restrict__ att_l,
                                                const float* __restrict__ att_r,
                                                float* __restrict__ al,
                                                float* __restrict__ ar,
                                                unsigned short* __restrict__ xbf,
                                                int N) {
  const int idx = blockIdx.x * 256 + threadIdx.x;
  if (idx >= N * NH) return;
  const int h = idx & (NH - 1);
  const float4* xp = (const float4*)(x + (size_t)idx * OC);
  const float4* lp = (const float4*)(att_l + h * OC);
  const float4* rp = (const float4*)(att_r + h * OC);
  float sl = 0.f, sr = 0.f;
  unsigned short* bp = xbf + (size_t)idx * OC;
#pragma unroll
  for (int q = 0; q < 4; ++q) {
    const float4 xv = xp[q], lv = lp[q], rv = rp[q];
    sl += xv.x * lv.x + xv.y * lv.y + xv.z * lv.z + xv.w * lv.w;
    sr += xv.x * rv.x + xv.y * rv.y + xv.z * rv.z + xv.w * rv.w;
    *(ushort4*)(bp + q * 4) =
        make_ushort4(bf16_rne(xv.x), bf16_rne(xv.y), bf16_rne(xv.z), bf16_rne(xv.w));
  }
  al[idx] = sl;
  ar[idx] = sr;
}

// ---------------- K2: histogram of edge destinations ---------------------
__global__ __launch_bounds__(256) void k2_count(const int* __restrict__ edst,
                                                int* __restrict__ count, int E) {
  const int e = blockIdx.x * 256 + threadIdx.x;
  if (e < E) atomicAdd(&count[edst[e]], 1);
}

// ---------------- K3a/b/c: hierarchical exclusive scan of counts ---------
__global__ __launch_bounds__(256) void k3a_partial(const int* __restrict__ count,
                                                   int* __restrict__ bsum, int N) {
  __shared__ int s[256];
  const int b = blockIdx.x, t = threadIdx.x;
  const int base = b * 512;
  int v = 0;
  if (base + t < N) v += count[base + t];
  if (base + 256 + t < N) v += count[base + 256 + t];
  s[t] = v;
  __syncthreads();
  for (int off = 128; off > 0; off >>= 1) {
    if (t < off) s[t] += s[t + off];
    __syncthreads();
  }
  if (t == 0) bsum[b] = s[0];
}

__global__ __launch_bounds__(SCAN_BLOCKS) void k3b_scanb(const int* __restrict__ bsum,
                                                         int* __restrict__ bofs,
                                                         int* __restrict__ row_start,
                                                         int N) {
  __shared__ int s[SCAN_BLOCKS];
  const int t = threadIdx.x;
  const int own = bsum[t];
  s[t] = own;
  __syncthreads();
  for (int off = 1; off < SCAN_BLOCKS; off <<= 1) {
    const int add = (t >= off) ? s[t - off] : 0;
    __syncthreads();
    s[t] += add;
    __syncthreads();
  }
  bofs[t] = s[t] - own;  // exclusive
  if (t == SCAN_BLOCKS - 1) row_start[N] = s[t];
}

__global__ __launch_bounds__(256) void k3c_scanc(const int* __restrict__ count,
                                                 const int* __restrict__ bofs,
                                                 int* __restrict__ row_start,
                                                 int* __restrict__ cursor, int N) {
  __shared__ int ps[256];
  const int b = blockIdx.x, t = threadIdx.x;
  const int base = b * 512;
  const int i0 = base + 2 * t, i1 = i0 + 1;
  const int c0 = (i0 < N) ? count[i0] : 0;
  const int c1 = (i1 < N) ? count[i1] : 0;
  const int pair = c0 + c1;
  ps[t] = pair;
  __syncthreads();
  for (int off = 1; off < 256; off <<= 1) {
    const int add = (t >= off) ? ps[t - off] : 0;
    __syncthreads();
    ps[t] += add;
    __syncthreads();
  }
  const int ex = bofs[b] + ps[t] - pair;  // exclusive prefix of pair t
  if (i0 < N) { row_start[i0] = ex; cursor[i0] = ex; }
  if (i1 < N) { row_start[i1] = ex + c0; cursor[i1] = ex + c0; }
}

// ---------------- K4: scatter packed (src, weight) into CSR buckets ------
__global__ __launch_bounds__(256) void k4_pack(const int* __restrict__ esrc,
                                               const int* __restrict__ edst,
                                               const float* __restrict__ ew,
                                               int* __restrict__ cursor,
                                               uint2* __restrict__ packed, int E) {
  const int e = blockIdx.x * 256 + threadIdx.x;
  if (e >= E) return;
  const int sN = esrc[e], dN = edst[e];
  const unsigned int wb = __float_as_uint(ew[e]);
  const int pos = atomicAdd(&cursor[dN], 1);
  packed[pos] = make_uint2((unsigned int)sN, wb);
}

// ---------------- K5: alpha recompute + softmax + bf16 gather-accum ------
__global__ __launch_bounds__(128) void k5_agg(const unsigned short* __restrict__ xbf,
                                              const uint2* __restrict__ packed,
                                              const int* __restrict__ row_start,
                                              const float* __restrict__ al,
                                              const float* __restrict__ ar,
                                              float* __restrict__ out, int N) {
  const int n = blockIdx.x;
  const int t = threadIdx.x;
  const int s0 = row_start[n];
  const int En = row_start[n + 1] - s0;
  __shared__ float red[128];
  __shared__ float mx[NH];
  __shared__ float inv8[NH];
  __shared__ float arn[NH];
  __shared__ float ebuf[CHUNK * NH];
  __shared__ float wbuf[CHUNK];
  __shared__ int sbuf[CHUNK];
  const int h_a = t & 7, i_a = t >> 3;
  if (t < NH) arn[t] = ar[(size_t)n * NH + t];
  __syncthreads();

  // ---- pass 1: per-head max; stash alpha in ebuf (valid iff En<=CHUNK) ---
  float lm = -INFINITY;
  for (int base = 0; base < En; base += CHUNK) {
    const int cnt = min(CHUNK, En - base);
    __syncthreads();
    for (int i = t; i < cnt; i += 128) {
      const uint2 p = packed[s0 + base + i];
      sbuf[i] = (int)p.x;
      wbuf[i] = __uint_as_float(p.y);
    }
    __syncthreads();
    for (int i = i_a; i < cnt; i += 16) {
      float a = wbuf[i] * (al[(size_t)sbuf[i] * NH + h_a] + arn[h_a]);
      a = (a > 0.f) ? a : 0.2f * a;
      ebuf[i * NH + h_a] = a;
      lm = fmaxf(lm, a);
    }
  }
  red[t] = lm;
  __syncthreads();
  if (t < NH) {
    float m = red[t];
    for (int j = 1; j < 16; ++j) m = fmaxf(m, red[j * NH + t]);
    mx[t] = m;
  }
  __syncthreads();

  const int h_b = t >> 4, c = t & 15;
  float dpart = 0.f, facc = 0.f;
  if (En <= CHUNK) {
    for (int i = i_a; i < En; i += 16) {
      const float e = __expf(ebuf[i * NH + h_a] - mx[h_a]);
      ebuf[i * NH + h_a] = e;
      dpart += e;
    }
    __syncthreads();
    for (int i = 0; i < En; ++i) {
      const float xv = bf16_to_f(xbf[(size_t)sbuf[i] * HC + h_b * OC + c]);
      facc = fmaf(ebuf[i * NH + h_b], xv, facc);
    }
  } else {
    for (int base = 0; base < En; base += CHUNK) {
      const int cnt = min(CHUNK, En - base);
      __syncthreads();
      for (int i = t; i < cnt; i += 128) {
        const uint2 p = packed[s0 + base + i];
        sbuf[i] = (int)p.x;
        wbuf[i] = __uint_as_float(p.y);
      }
      __syncthreads();
      for (int i = i_a; i < cnt; i += 16) {
        float a = wbuf[i] * (al[(size_t)sbuf[i] * NH + h_a] + arn[h_a]);
        a = (a > 0.f) ? a : 0.2f * a;
        const float e = __expf(a - mx[h_a]);
        ebuf[i * NH + h_a] = e;
        dpart += e;
      }
      __syncthreads();
      for (int i = 0; i < cnt; ++i) {
        const float xv = bf16_to_f(xbf[(size_t)sbuf[i] * HC + h_b * OC + c]);
        facc = fmaf(ebuf[i * NH + h_b], xv, facc);
      }
    }
  }
  __syncthreads();

  red[t] = dpart;
  __syncthreads();
  if (t < NH) {
    float sden = 0.f;
    for (int j = 0; j < 16; ++j) sden += red[j * NH + t];
    inv8[t] = 1.f / sden;
  }
  __syncthreads();

  const float feat = (En > 0) ? facc * inv8[h_b] : 0.f;
  const float o = (feat > 0.f) ? feat : (__expf(feat) - 1.f);  // elu
  out[(size_t)n * HC + t] += o;  // out already holds the residual from k1
}

extern "C" void kernel_launch(void* const* d_in, const int* in_sizes, int n_in,
                              void* d_out, int out_size, void* d_ws, size_t ws_size,
                              hipStream_t stream) {
  const float* feature = (const float*)d_in[0];
  const int* esrc = (const int*)d_in[1];
  const int* edst = (const int*)d_in[2];
  const float* ew = (const float*)d_in[3];
  const float* w_lin = (const float*)d_in[4];
  const float* att_l = (const float*)d_in[5];
  const float* att_r = (const float*)d_in[6];
  const float* w_res = (const float*)d_in[7];
  float* out = (float*)d_out;

  const int N = in_sizes[0] / IN_DIM;
  const int E = in_sizes[1];

  char* ws = (char*)d_ws;
  size_t off = 0;
  auto alloc = [&](size_t bytes) {
    void* p = ws + off;
    off = (off + bytes + 255) & ~(size_t)255;
    return p;
  };
  float* x = (float*)alloc((size_t)N * HC * sizeof(float));
  unsigned short* xbf = (unsigned short*)alloc((size_t)N * HC * sizeof(unsigned short));
  float* al = (float*)alloc((size_t)N * NH * sizeof(float));
  float* ar = (float*)alloc((size_t)N * NH * sizeof(float));
  int* count = (int*)alloc((size_t)N * sizeof(int));
  int* row_start = (int*)alloc((size_t)(N + 1) * sizeof(int));
  int* cursor = (int*)alloc((size_t)N * sizeof(int));
  int* bsum = (int*)alloc((size_t)SCAN_BLOCKS * sizeof(int));
  int* bofs = (int*)alloc((size_t)SCAN_BLOCKS * sizeof(int));
  uint2* packed = (uint2*)alloc((size_t)E * sizeof(uint2));

  hipMemsetAsync(count, 0, (size_t)N * sizeof(int), stream);
  k1_mfma<<<256, 256, 0, stream>>>(feature, w_lin, w_res, x, out, N);
  k1b_attn<<<(N * NH + 255) / 256, 256, 0, stream>>>(x, att_l, att_r, al, ar, xbf, N);
  k2_count<<<(E + 255) / 256, 256, 0, stream>>>(edst, count, E);
  k3a_partial<<<SCAN_BLOCKS, 256, 0, stream>>>(count, bsum, N);
  k3b_scanb<<<1, SCAN_BLOCKS, 0, stream>>>(bsum, bofs, row_start, N);
  k3c_scanc<<<SCAN_BLOCKS, 256, 0, stream>>>(count, bofs, row_start, cursor, N);
  k4_pack<<<(E + 255) / 256, 256, 0, stream>>>(esrc, edst, ew, cursor, packed, E);
  k5_agg<<<N, 128, 0, stream>>>(xbf, packed, row_start, al, ar, out, N);
}

// Round 5
// 308.836 us; speedup vs baseline: 1.8182x; 1.3900x over previous
//
#include <hip/hip_runtime.h>
#include <math.h>

#define IN_DIM 128
#define NH 8
#define OC 16
#define HC 128   // NH*OC
#define CHUNK 128  // k5 LDS chunk
#define BSTR 136   // padded bf16 LDS stride (16B-aligned rows)
#define DPB 256    // dst nodes per coarse bin (bin = dst >> 8)
#define NBMAX 256
#define ECH 4096   // edges per chunk in binning kernels

typedef __attribute__((ext_vector_type(8))) short short8;
typedef __attribute__((ext_vector_type(4))) float f32x4;

__device__ __forceinline__ unsigned short bf16_rne(float f) {
  unsigned int u = __builtin_bit_cast(unsigned int, f);
  u += 0x7FFFu + ((u >> 16) & 1u);
  return (unsigned short)(u >> 16);
}
__device__ __forceinline__ float bf16_to_f(unsigned short h) {
  unsigned int u = ((unsigned int)h) << 16;
  return __builtin_bit_cast(float, u);
}

// ---------------- K1a: xbf = bf16(feature @ w_lin), single-bf16 MFMA -----
// 35 KB LDS -> 4 blocks/CU possible; w_lin staged coalesced.
__global__ __launch_bounds__(256) void k1a_xlin(const float* __restrict__ feature,
                                                const float* __restrict__ w_lin,
                                                unsigned short* __restrict__ xbf,
                                                int N) {
  __shared__ unsigned short Bh[HC * BSTR];  // 34.8 KB
  const int t = threadIdx.x;
  for (int i = t; i < IN_DIM * HC; i += 256) {
    const int r = i >> 7, c = i & 127;  // w_lin[k=r][col=c]
    Bh[c * BSTR + r] = bf16_rne(w_lin[i]);
  }
  __syncthreads();

  const int wave = t >> 6, lane = t & 63;
  const int n16 = lane & 15, quad = lane >> 4;
  const int nStrips = (N + 15) >> 4;

  for (int strip = blockIdx.x * 4 + wave; strip < nStrips; strip += gridDim.x * 4) {
    const int row0 = strip * 16;
    const int arow = row0 + n16;
    const float* __restrict__ ap =
        feature + (size_t)((arow < N) ? arow : 0) * IN_DIM + quad * 8;
    short8 ah[4];
#pragma unroll
    for (int ks = 0; ks < 4; ++ks) {
      const float4 f0 = *(const float4*)(ap + ks * 32);
      const float4 f1 = *(const float4*)(ap + ks * 32 + 4);
      const float fv[8] = {f0.x, f0.y, f0.z, f0.w, f1.x, f1.y, f1.z, f1.w};
      short8 h;
#pragma unroll
      for (int j = 0; j < 8; ++j) h[j] = (short)bf16_rne(fv[j]);
      ah[ks] = h;
    }
#pragma unroll
    for (int cg = 0; cg < 2; ++cg) {
      f32x4 acc[4] = {{0.f,0.f,0.f,0.f},{0.f,0.f,0.f,0.f},{0.f,0.f,0.f,0.f},{0.f,0.f,0.f,0.f}};
#pragma unroll
      for (int ks = 0; ks < 4; ++ks) {
#pragma unroll
        for (int j = 0; j < 4; ++j) {
          const int boff = ((cg * 4 + j) * 16 + n16) * BSTR + ks * 32 + quad * 8;
          const short8 bh = *(const short8*)&Bh[boff];
          acc[j] = __builtin_amdgcn_mfma_f32_16x16x32_bf16(ah[ks], bh, acc[j], 0, 0, 0);
        }
      }
#pragma unroll
      for (int j = 0; j < 4; ++j) {
        const int colo = (cg * 4 + j) * 16 + n16;
#pragma unroll
        for (int r = 0; r < 4; ++r) {
          const int rr = row0 + quad * 4 + r;
          if (rr < N) xbf[(size_t)rr * HC + colo] = bf16_rne(acc[j][r]);
        }
      }
    }
  }
}

// ---------------- K1c: out = feature @ w_res (residual), split-bf16 ------
__global__ __launch_bounds__(256) void k1c_res(const float* __restrict__ feature,
                                               const float* __restrict__ w_res,
                                               float* __restrict__ out, int N) {
  __shared__ unsigned short Bhi[HC * BSTR];  // 34.8 KB
  __shared__ unsigned short Blo[HC * BSTR];  // 34.8 KB
  const int t = threadIdx.x;
  for (int i = t; i < IN_DIM * HC; i += 256) {
    const int r = i >> 7, c = i & 127;
    const float f = w_res[i];
    const unsigned short hh = bf16_rne(f);
    Bhi[c * BSTR + r] = hh;
    Blo[c * BSTR + r] = bf16_rne(f - bf16_to_f(hh));
  }
  __syncthreads();

  const int wave = t >> 6, lane = t & 63;
  const int n16 = lane & 15, quad = lane >> 4;
  const int nStrips = (N + 15) >> 4;

  for (int strip = blockIdx.x * 4 + wave; strip < nStrips; strip += gridDim.x * 4) {
    const int row0 = strip * 16;
    const int arow = row0 + n16;
    const float* __restrict__ ap =
        feature + (size_t)((arow < N) ? arow : 0) * IN_DIM + quad * 8;
    short8 ahi[4], alo[4];
#pragma unroll
    for (int ks = 0; ks < 4; ++ks) {
      const float4 f0 = *(const float4*)(ap + ks * 32);
      const float4 f1 = *(const float4*)(ap + ks * 32 + 4);
      const float fv[8] = {f0.x, f0.y, f0.z, f0.w, f1.x, f1.y, f1.z, f1.w};
      short8 h, l;
#pragma unroll
      for (int j = 0; j < 8; ++j) {
        const unsigned short hh = bf16_rne(fv[j]);
        h[j] = (short)hh;
        l[j] = (short)bf16_rne(fv[j] - bf16_to_f(hh));
      }
      ahi[ks] = h;
      alo[ks] = l;
    }
#pragma unroll
    for (int cg = 0; cg < 2; ++cg) {
      f32x4 acc[4] = {{0.f,0.f,0.f,0.f},{0.f,0.f,0.f,0.f},{0.f,0.f,0.f,0.f},{0.f,0.f,0.f,0.f}};
#pragma unroll
      for (int ks = 0; ks < 4; ++ks) {
#pragma unroll
        for (int j = 0; j < 4; ++j) {
          const int boff = ((cg * 4 + j) * 16 + n16) * BSTR + ks * 32 + quad * 8;
          const short8 bh = *(const short8*)&Bhi[boff];
          const short8 bl = *(const short8*)&Blo[boff];
          acc[j] = __builtin_amdgcn_mfma_f32_16x16x32_bf16(ahi[ks], bh, acc[j], 0, 0, 0);
          acc[j] = __builtin_amdgcn_mfma_f32_16x16x32_bf16(ahi[ks], bl, acc[j], 0, 0, 0);
          acc[j] = __builtin_amdgcn_mfma_f32_16x16x32_bf16(alo[ks], bh, acc[j], 0, 0, 0);
        }
      }
#pragma unroll
      for (int j = 0; j < 4; ++j) {
        const int colo = (cg * 4 + j) * 16 + n16;
#pragma unroll
        for (int r = 0; r < 4; ++r) {
          const int rr = row0 + quad * 4 + r;
          if (rr < N) out[(size_t)rr * HC + colo] = acc[j][r];
        }
      }
    }
  }
}

// ---------------- K1b: al/ar logits from xbf -----------------------------
__global__ __launch_bounds__(256) void k1b_attn(const unsigned short* __restrict__ xbf,
                                                const float* __restrict__ att_l,
                                                const float* __restrict__ att_r,
                                                float* __restrict__ al,
                                                float* __restrict__ ar, int N) {
  const int idx = blockIdx.x * 256 + threadIdx.x;
  if (idx >= N * NH) return;
  const int h = idx & (NH - 1);
  const ushort4* xp = (const ushort4*)(xbf + (size_t)idx * OC);
  const float4* lp = (const float4*)(att_l + h * OC);
  const float4* rp = (const float4*)(att_r + h * OC);
  float sl = 0.f, sr = 0.f;
#pragma unroll
  for (int q = 0; q < 4; ++q) {
    const ushort4 xu = xp[q];
    const float4 lv = lp[q], rv = rp[q];
    const float x0 = bf16_to_f(xu.x), x1 = bf16_to_f(xu.y);
    const float x2 = bf16_to_f(xu.z), x3 = bf16_to_f(xu.w);
    sl += x0 * lv.x + x1 * lv.y + x2 * lv.z + x3 * lv.w;
    sr += x0 * rv.x + x1 * rv.y + x2 * rv.z + x3 * rv.w;
  }
  al[idx] = sl;
  ar[idx] = sr;
}

// ---------------- K4a: coarse-bin histogram (bin = dst>>8) ---------------
__global__ __launch_bounds__(256) void k4a_count(const int* __restrict__ edst,
                                                 int* __restrict__ bin_count, int E) {
  __shared__ int cnt[NBMAX];
  const int t = threadIdx.x;
  cnt[t] = 0;
  __syncthreads();
  const int base = blockIdx.x * ECH;
#pragma unroll
  for (int j = 0; j < ECH / 256; ++j) {
    const int e = base + j * 256 + t;
    if (e < E) atomicAdd(&cnt[edst[e] >> 8], 1);
  }
  __syncthreads();
  if (cnt[t] > 0) atomicAdd(&bin_count[t], cnt[t]);
}

// ---------------- K3: scan bin counts -> bin_ofs / bin_cursor ------------
__global__ __launch_bounds__(NBMAX) void k3_bins(const int* __restrict__ bin_count,
                                                 int* __restrict__ bin_ofs,
                                                 int* __restrict__ bin_cursor,
                                                 int* __restrict__ row_start, int N) {
  __shared__ int s[NBMAX];
  const int t = threadIdx.x;
  const int own = bin_count[t];
  s[t] = own;
  __syncthreads();
  for (int o = 1; o < NBMAX; o <<= 1) {
    const int a = (t >= o) ? s[t - o] : 0;
    __syncthreads();
    s[t] += a;
    __syncthreads();
  }
  const int ex = s[t] - own;
  bin_ofs[t] = ex;
  bin_cursor[t] = ex;
  if (t == NBMAX - 1) {
    bin_ofs[NBMAX] = s[t];
    row_start[N] = s[t];  // = E
  }
}

// ---------------- K4b: bin-scatter with LDS write-combining --------------
// Stage chunk bin-ordered in LDS, reserve per-bin global runs (1 atomic per
// block*bin), then LINEAR copy LDS->global: consecutive lanes write
// consecutive addresses -> full-line stores (kills the 8x write amp).
__global__ __launch_bounds__(256) void k4b_bin(const int* __restrict__ esrc,
                                               const int* __restrict__ edst,
                                               const float* __restrict__ ew,
                                               int* __restrict__ bin_cursor,
                                               uint2* __restrict__ tmp, int E) {
  __shared__ int cnt[NBMAX];
  __shared__ int s[NBMAX];
  __shared__ int ofs[NBMAX];
  __shared__ int gbase[NBMAX];
  __shared__ uint2 data[ECH];  // 32 KB
  const int t = threadIdx.x;
  cnt[t] = 0;
  __syncthreads();
  const int base = blockIdx.x * ECH;
  uint2 v[16];
  int bj[16], sj[16];
#pragma unroll
  for (int j = 0; j < 16; ++j) {
    const int e = base + j * 256 + t;
    bj[j] = -1;
    if (e < E) {
      const int d = edst[e];
      v[j] = make_uint2((unsigned)esrc[e] | ((unsigned)(d & (DPB - 1)) << 16),
                        __float_as_uint(ew[e]));
      bj[j] = d >> 8;
      sj[j] = atomicAdd(&cnt[bj[j]], 1);
    }
  }
  __syncthreads();
  const int own = cnt[t];
  s[t] = own;
  __syncthreads();
  for (int o = 1; o < NBMAX; o <<= 1) {
    const int a = (t >= o) ? s[t - o] : 0;
    __syncthreads();
    s[t] += a;
    __syncthreads();
  }
  ofs[t] = s[t] - own;
  if (own > 0) gbase[t] = atomicAdd(&bin_cursor[t], own);
  __syncthreads();
#pragma unroll
  for (int j = 0; j < 16; ++j)
    if (bj[j] >= 0) data[ofs[bj[j]] + sj[j]] = v[j];
  __syncthreads();
  const int cc = (base + ECH <= E) ? ECH : (E - base);
  for (int i = t; i < cc; i += 256) {
    int lo = 0, hi = NBMAX - 1;  // ofs[255]=cc (tail bins empty): i < ofs[hi]
    while (hi - lo > 1) {
      const int mid = (lo + hi) >> 1;
      if (ofs[mid] <= i) lo = mid; else hi = mid;
    }
    tmp[gbase[lo] + (i - ofs[lo])] = data[i];
  }
}

// ---------------- K4c: per-bin dst-sort -> final CSR + row_start ---------
__global__ __launch_bounds__(256) void k4c_sort(const uint2* __restrict__ tmp,
                                                const int* __restrict__ bin_ofs,
                                                uint2* __restrict__ packed,
                                                int* __restrict__ row_start, int N) {
  const int b = blockIdx.x, t = threadIdx.x;
  const int gstart = bin_ofs[b];
  const int M = bin_ofs[b + 1] - gstart;
  __shared__ int cnt[DPB];
  __shared__ int s[DPB];
  __shared__ int cur[DPB];
  __shared__ int ccnt[DPB];
  __shared__ int cofs[DPB + 1];
  __shared__ uint2 data[ECH];  // 32 KB
  cnt[t] = 0;
  __syncthreads();
  for (int i = t; i < M; i += 256) atomicAdd(&cnt[tmp[gstart + i].x >> 16], 1);
  __syncthreads();
  {
    const int own = cnt[t];
    s[t] = own;
    __syncthreads();
    for (int o = 1; o < DPB; o <<= 1) {
      const int a = (t >= o) ? s[t - o] : 0;
      __syncthreads();
      s[t] += a;
      __syncthreads();
    }
    const int ex = s[t] - own;
    cur[t] = gstart + ex;
    const int node = b * DPB + t;
    if (node < N) row_start[node] = gstart + ex;
  }
  __syncthreads();
  for (int cb = 0; cb < M; cb += ECH) {
    const int cc = min(ECH, M - cb);
    ccnt[t] = 0;
    __syncthreads();
    uint2 v[16];
    int dj[16], sj[16];
#pragma unroll
    for (int j = 0; j < 16; ++j) {
      const int li = j * 256 + t;
      dj[j] = -1;
      if (li < cc) {
        v[j] = tmp[gstart + cb + li];
        dj[j] = (int)(v[j].x >> 16);
        sj[j] = atomicAdd(&ccnt[dj[j]], 1);
      }
    }
    __syncthreads();
    const int cown = ccnt[t];
    s[t] = cown;
    __syncthreads();
    for (int o = 1; o < DPB; o <<= 1) {
      const int a = (t >= o) ? s[t - o] : 0;
      __syncthreads();
      s[t] += a;
      __syncthreads();
    }
    cofs[t] = s[t] - cown;
    if (t == 0) cofs[DPB] = cc;
    __syncthreads();
#pragma unroll
    for (int j = 0; j < 16; ++j)
      if (dj[j] >= 0) data[cofs[dj[j]] + sj[j]] = make_uint2(v[j].x & 0xFFFFu, v[j].y);
    __syncthreads();
    for (int i = t; i < cc; i += 256) {
      int lo = 0, hi = DPB;
      while (hi - lo > 1) {
        const int mid = (lo + hi) >> 1;
        if (cofs[mid] <= i) lo = mid; else hi = mid;
      }
      packed[cur[lo] + (i - cofs[lo])] = data[i];
    }
    __syncthreads();
    cur[t] += ccnt[t];
    __syncthreads();
  }
}

// ---------------- K5: alpha recompute + softmax + bf16 gather-accum ------
__global__ __launch_bounds__(128) void k5_agg(const unsigned short* __restrict__ xbf,
                                              const uint2* __restrict__ packed,
                                              const int* __restrict__ row_start,
                                              const float* __restrict__ al,
                                              const float* __restrict__ ar,
                                              float* __restrict__ out, int N) {
  const int n = blockIdx.x;
  const int t = threadIdx.x;
  const int s0 = row_start[n];
  const int En = row_start[n + 1] - s0;
  __shared__ float red[128];
  __shared__ float mx[NH];
  __shared__ float inv8[NH];
  __shared__ float arn[NH];
  __shared__ float ebuf[CHUNK * NH];
  __shared__ float wbuf[CHUNK];
  __shared__ int sbuf[CHUNK];
  const int h_a = t & 7, i_a = t >> 3;
  if (t < NH) arn[t] = ar[(size_t)n * NH + t];
  __syncthreads();

  float lm = -INFINITY;
  for (int base = 0; base < En; base += CHUNK) {
    const int cnt = min(CHUNK, En - base);
    __syncthreads();
    for (int i = t; i < cnt; i += 128) {
      const uint2 p = packed[s0 + base + i];
      sbuf[i] = (int)p.x;
      wbuf[i] = __uint_as_float(p.y);
    }
    __syncthreads();
    for (int i = i_a; i < cnt; i += 16) {
      float a = wbuf[i] * (al[(size_t)sbuf[i] * NH + h_a] + arn[h_a]);
      a = (a > 0.f) ? a : 0.2f * a;
      ebuf[i * NH + h_a] = a;
      lm = fmaxf(lm, a);
    }
  }
  red[t] = lm;
  __syncthreads();
  if (t < NH) {
    float m = red[t];
    for (int j = 1; j < 16; ++j) m = fmaxf(m, red[j * NH + t]);
    mx[t] = m;
  }
  __syncthreads();

  const int h_b = t >> 4, c = t & 15;
  float dpart = 0.f, facc = 0.f;
  if (En <= CHUNK) {
    for (int i = i_a; i < En; i += 16) {
      const float e = __expf(ebuf[i * NH + h_a] - mx[h_a]);
      ebuf[i * NH + h_a] = e;
      dpart += e;
    }
    __syncthreads();
    for (int i = 0; i < En; ++i) {
      const float xv = bf16_to_f(xbf[(size_t)sbuf[i] * HC + h_b * OC + c]);
      facc = fmaf(ebuf[i * NH + h_b], xv, facc);
    }
  } else {
    for (int base = 0; base < En; base += CHUNK) {
      const int cnt = min(CHUNK, En - base);
      __syncthreads();
      for (int i = t; i < cnt; i += 128) {
        const uint2 p = packed[s0 + base + i];
        sbuf[i] = (int)p.x;
        wbuf[i] = __uint_as_float(p.y);
      }
      __syncthreads();
      for (int i = i_a; i < cnt; i += 16) {
        float a = wbuf[i] * (al[(size_t)sbuf[i] * NH + h_a] + arn[h_a]);
        a = (a > 0.f) ? a : 0.2f * a;
        const float e = __expf(a - mx[h_a]);
        ebuf[i * NH + h_a] = e;
        dpart += e;
      }
      __syncthreads();
      for (int i = 0; i < cnt; ++i) {
        const float xv = bf16_to_f(xbf[(size_t)sbuf[i] * HC + h_b * OC + c]);
        facc = fmaf(ebuf[i * NH + h_b], xv, facc);
      }
    }
  }
  __syncthreads();

  red[t] = dpart;
  __syncthreads();
  if (t < NH) {
    float sden = 0.f;
    for (int j = 0; j < 16; ++j) sden += red[j * NH + t];
    inv8[t] = 1.f / sden;
  }
  __syncthreads();

  const float feat = (En > 0) ? facc * inv8[h_b] : 0.f;
  const float o = (feat > 0.f) ? feat : (__expf(feat) - 1.f);  // elu
  out[(size_t)n * HC + t] += o;  // out already holds the residual from k1c
}

extern "C" void kernel_launch(void* const* d_in, const int* in_sizes, int n_in,
                              void* d_out, int out_size, void* d_ws, size_t ws_size,
                              hipStream_t stream) {
  const float* feature = (const float*)d_in[0];
  const int* esrc = (const int*)d_in[1];
  const int* edst = (const int*)d_in[2];
  const float* ew = (const float*)d_in[3];
  const float* w_lin = (const float*)d_in[4];
  const float* att_l = (const float*)d_in[5];
  const float* att_r = (const float*)d_in[6];
  const float* w_res = (const float*)d_in[7];
  float* out = (float*)d_out;

  const int N = in_sizes[0] / IN_DIM;
  const int E = in_sizes[1];
  const int NB = (N + DPB - 1) / DPB;
  const int nch = (E + ECH - 1) / ECH;

  char* ws = (char*)d_ws;
  size_t off = 0;
  auto alloc = [&](size_t bytes) {
    void* p = ws + off;
    off = (off + bytes + 255) & ~(size_t)255;
    return p;
  };
  unsigned short* xbf = (unsigned short*)alloc((size_t)N * HC * sizeof(unsigned short));
  float* al = (float*)alloc((size_t)N * NH * sizeof(float));
  float* ar = (float*)alloc((size_t)N * NH * sizeof(float));
  int* row_start = (int*)alloc((size_t)(N + 1) * sizeof(int));
  int* bin_count = (int*)alloc((size_t)NBMAX * sizeof(int));
  int* bin_ofs = (int*)alloc((size_t)(NBMAX + 1) * sizeof(int));
  int* bin_cursor = (int*)alloc((size_t)NBMAX * sizeof(int));
  uint2* tmp = (uint2*)alloc((size_t)E * sizeof(uint2));
  uint2* packed = (uint2*)alloc((size_t)E * sizeof(uint2));

  hipMemsetAsync(bin_count, 0, (size_t)NBMAX * sizeof(int), stream);
  k1c_res<<<512, 256, 0, stream>>>(feature, w_res, out, N);
  k1a_xlin<<<512, 256, 0, stream>>>(feature, w_lin, xbf, N);
  k1b_attn<<<(N * NH + 255) / 256, 256, 0, stream>>>(xbf, att_l, att_r, al, ar, N);
  k4a_count<<<nch, 256, 0, stream>>>(edst, bin_count, E);
  k3_bins<<<1, NBMAX, 0, stream>>>(bin_count, bin_ofs, bin_cursor, row_start, N);
  k4b_bin<<<nch, 256, 0, stream>>>(esrc, edst, ew, bin_cursor, tmp, E);
  k4c_sort<<<NB, 256, 0, stream>>>(tmp, bin_ofs, packed, row_start, N);
  k5_agg<<<N, 128, 0, stream>>>(xbf, packed, row_start, al, ar, out, N);
}

// Round 6
// 298.434 us; speedup vs baseline: 1.8815x; 1.0349x over previous
//
#include <hip/hip_runtime.h>
#include <math.h>

#define IN_DIM 128
#define NH 8
#define OC 16
#define HC 128   // NH*OC
#define CHUNK 128  // k5 LDS chunk
#define BSTR 136   // padded bf16 LDS stride (16B-aligned rows)
#define DPB 256    // dst nodes per coarse bin (bin = dst >> 8)
#define NBMAX 256
#define ECH 4096   // edges per chunk in binning kernels

typedef __attribute__((ext_vector_type(8))) short short8;
typedef __attribute__((ext_vector_type(4))) float f32x4;

__device__ __forceinline__ unsigned short bf16_rne(float f) {
  unsigned int u = __builtin_bit_cast(unsigned int, f);
  u += 0x7FFFu + ((u >> 16) & 1u);
  return (unsigned short)(u >> 16);
}
__device__ __forceinline__ float bf16_to_f(unsigned short h) {
  unsigned int u = ((unsigned int)h) << 16;
  return __builtin_bit_cast(float, u);
}

// ---------------- K1: xbf = bf16(feature@w_lin), out = feature@w_res -----
// Fused: feature read ONCE, split-A (Ahi+Alo) shared by both products,
// B = bf16-hi only (B-rounding error ~0.002 abs, negligible).
// LDS 69.6 KB -> 2 blocks/CU.
__global__ __launch_bounds__(256) void k1_fused(const float* __restrict__ feature,
                                                const float* __restrict__ w_lin,
                                                const float* __restrict__ w_res,
                                                unsigned short* __restrict__ xbf,
                                                float* __restrict__ out, int N) {
  __shared__ unsigned short BL[HC * BSTR];  // 34.8 KB  w_lin^T hi
  __shared__ unsigned short BR[HC * BSTR];  // 34.8 KB  w_res^T hi
  const int t = threadIdx.x;
  for (int i = t; i < IN_DIM * HC; i += 256) {
    const int r = i >> 7, c = i & 127;  // W[k=r][col=c]
    BL[c * BSTR + r] = bf16_rne(w_lin[i]);
    BR[c * BSTR + r] = bf16_rne(w_res[i]);
  }
  __syncthreads();

  const int wave = t >> 6, lane = t & 63;
  const int n16 = lane & 15, quad = lane >> 4;
  const int nStrips = (N + 15) >> 4;

  for (int strip = blockIdx.x * 4 + wave; strip < nStrips; strip += gridDim.x * 4) {
    const int row0 = strip * 16;
    const int arow = row0 + n16;
    const float* __restrict__ ap =
        feature + (size_t)((arow < N) ? arow : 0) * IN_DIM + quad * 8;
    short8 ahi[4], alo[4];
#pragma unroll
    for (int ks = 0; ks < 4; ++ks) {
      const float4 f0 = *(const float4*)(ap + ks * 32);
      const float4 f1 = *(const float4*)(ap + ks * 32 + 4);
      const float fv[8] = {f0.x, f0.y, f0.z, f0.w, f1.x, f1.y, f1.z, f1.w};
      short8 h, l;
#pragma unroll
      for (int j = 0; j < 8; ++j) {
        const unsigned short hh = bf16_rne(fv[j]);
        h[j] = (short)hh;
        l[j] = (short)bf16_rne(fv[j] - bf16_to_f(hh));
      }
      ahi[ks] = h;
      alo[ks] = l;
    }
    // ---- product 1: x = f @ w_lin -> bf16 ----
#pragma unroll
    for (int cg = 0; cg < 2; ++cg) {
      f32x4 acc[4] = {{0.f,0.f,0.f,0.f},{0.f,0.f,0.f,0.f},{0.f,0.f,0.f,0.f},{0.f,0.f,0.f,0.f}};
#pragma unroll
      for (int ks = 0; ks < 4; ++ks) {
#pragma unroll
        for (int j = 0; j < 4; ++j) {
          const int boff = ((cg * 4 + j) * 16 + n16) * BSTR + ks * 32 + quad * 8;
          const short8 bh = *(const short8*)&BL[boff];
          acc[j] = __builtin_amdgcn_mfma_f32_16x16x32_bf16(ahi[ks], bh, acc[j], 0, 0, 0);
          acc[j] = __builtin_amdgcn_mfma_f32_16x16x32_bf16(alo[ks], bh, acc[j], 0, 0, 0);
        }
      }
#pragma unroll
      for (int j = 0; j < 4; ++j) {
        const int colo = (cg * 4 + j) * 16 + n16;
#pragma unroll
        for (int r = 0; r < 4; ++r) {
          const int rr = row0 + quad * 4 + r;
          if (rr < N) xbf[(size_t)rr * HC + colo] = bf16_rne(acc[j][r]);
        }
      }
    }
    // ---- product 2: residual = f @ w_res -> fp32 out ----
#pragma unroll
    for (int cg = 0; cg < 2; ++cg) {
      f32x4 acc[4] = {{0.f,0.f,0.f,0.f},{0.f,0.f,0.f,0.f},{0.f,0.f,0.f,0.f},{0.f,0.f,0.f,0.f}};
#pragma unroll
      for (int ks = 0; ks < 4; ++ks) {
#pragma unroll
        for (int j = 0; j < 4; ++j) {
          const int boff = ((cg * 4 + j) * 16 + n16) * BSTR + ks * 32 + quad * 8;
          const short8 bh = *(const short8*)&BR[boff];
          acc[j] = __builtin_amdgcn_mfma_f32_16x16x32_bf16(ahi[ks], bh, acc[j], 0, 0, 0);
          acc[j] = __builtin_amdgcn_mfma_f32_16x16x32_bf16(alo[ks], bh, acc[j], 0, 0, 0);
        }
      }
#pragma unroll
      for (int j = 0; j < 4; ++j) {
        const int colo = (cg * 4 + j) * 16 + n16;
#pragma unroll
        for (int r = 0; r < 4; ++r) {
          const int rr = row0 + quad * 4 + r;
          if (rr < N) out[(size_t)rr * HC + colo] = acc[j][r];
        }
      }
    }
  }
}

// ---------------- K1b: al/ar logits from xbf -----------------------------
__global__ __launch_bounds__(256) void k1b_attn(const unsigned short* __restrict__ xbf,
                                                const float* __restrict__ att_l,
                                                const float* __restrict__ att_r,
                                                float* __restrict__ al,
                                                float* __restrict__ ar, int N) {
  const int idx = blockIdx.x * 256 + threadIdx.x;
  if (idx >= N * NH) return;
  const int h = idx & (NH - 1);
  const ushort4* xp = (const ushort4*)(xbf + (size_t)idx * OC);
  const float4* lp = (const float4*)(att_l + h * OC);
  const float4* rp = (const float4*)(att_r + h * OC);
  float sl = 0.f, sr = 0.f;
#pragma unroll
  for (int q = 0; q < 4; ++q) {
    const ushort4 xu = xp[q];
    const float4 lv = lp[q], rv = rp[q];
    const float x0 = bf16_to_f(xu.x), x1 = bf16_to_f(xu.y);
    const float x2 = bf16_to_f(xu.z), x3 = bf16_to_f(xu.w);
    sl += x0 * lv.x + x1 * lv.y + x2 * lv.z + x3 * lv.w;
    sr += x0 * rv.x + x1 * rv.y + x2 * rv.z + x3 * rv.w;
  }
  al[idx] = sl;
  ar[idx] = sr;
}

// ---------------- K4a: coarse-bin histogram (bin = dst>>8) ---------------
__global__ __launch_bounds__(256) void k4a_count(const int* __restrict__ edst,
                                                 int* __restrict__ bin_count, int E) {
  __shared__ int cnt[NBMAX];
  const int t = threadIdx.x;
  cnt[t] = 0;
  __syncthreads();
  const int base = blockIdx.x * ECH;
#pragma unroll
  for (int j = 0; j < ECH / 256; ++j) {
    const int e = base + j * 256 + t;
    if (e < E) atomicAdd(&cnt[edst[e] >> 8], 1);
  }
  __syncthreads();
  if (cnt[t] > 0) atomicAdd(&bin_count[t], cnt[t]);
}

// ---------------- K3: scan bin counts -> bin_ofs / bin_cursor ------------
__global__ __launch_bounds__(NBMAX) void k3_bins(const int* __restrict__ bin_count,
                                                 int* __restrict__ bin_ofs,
                                                 int* __restrict__ bin_cursor,
                                                 int* __restrict__ row_start, int N) {
  __shared__ int s[NBMAX];
  const int t = threadIdx.x;
  const int own = bin_count[t];
  s[t] = own;
  __syncthreads();
  for (int o = 1; o < NBMAX; o <<= 1) {
    const int a = (t >= o) ? s[t - o] : 0;
    __syncthreads();
    s[t] += a;
    __syncthreads();
  }
  const int ex = s[t] - own;
  bin_ofs[t] = ex;
  bin_cursor[t] = ex;
  if (t == NBMAX - 1) {
    bin_ofs[NBMAX] = s[t];
    row_start[N] = s[t];  // = E
  }
}

// ---------------- K4b: bin-scatter with LDS write-combining --------------
__global__ __launch_bounds__(256) void k4b_bin(const int* __restrict__ esrc,
                                               const int* __restrict__ edst,
                                               const float* __restrict__ ew,
                                               int* __restrict__ bin_cursor,
                                               uint2* __restrict__ tmp, int E) {
  __shared__ int cnt[NBMAX];
  __shared__ int s[NBMAX];
  __shared__ int ofs[NBMAX];
  __shared__ int gbase[NBMAX];
  __shared__ uint2 data[ECH];  // 32 KB
  const int t = threadIdx.x;
  cnt[t] = 0;
  __syncthreads();
  const int base = blockIdx.x * ECH;
  uint2 v[16];
  int bj[16], sj[16];
#pragma unroll
  for (int j = 0; j < 16; ++j) {
    const int e = base + j * 256 + t;
    bj[j] = -1;
    if (e < E) {
      const int d = edst[e];
      v[j] = make_uint2((unsigned)esrc[e] | ((unsigned)(d & (DPB - 1)) << 16),
                        __float_as_uint(ew[e]));
      bj[j] = d >> 8;
      sj[j] = atomicAdd(&cnt[bj[j]], 1);
    }
  }
  __syncthreads();
  const int own = cnt[t];
  s[t] = own;
  __syncthreads();
  for (int o = 1; o < NBMAX; o <<= 1) {
    const int a = (t >= o) ? s[t - o] : 0;
    __syncthreads();
    s[t] += a;
    __syncthreads();
  }
  ofs[t] = s[t] - own;
  if (own > 0) gbase[t] = atomicAdd(&bin_cursor[t], own);
  __syncthreads();
#pragma unroll
  for (int j = 0; j < 16; ++j)
    if (bj[j] >= 0) data[ofs[bj[j]] + sj[j]] = v[j];
  __syncthreads();
  const int cc = (base + ECH <= E) ? ECH : (E - base);
  for (int i = t; i < cc; i += 256) {
    int lo = 0, hi = NBMAX - 1;
    while (hi - lo > 1) {
      const int mid = (lo + hi) >> 1;
      if (ofs[mid] <= i) lo = mid; else hi = mid;
    }
    tmp[gbase[lo] + (i - ofs[lo])] = data[i];
  }
}

// ---------------- K4c: per-bin dst-sort -> final CSR + row_start ---------
__global__ __launch_bounds__(256) void k4c_sort(const uint2* __restrict__ tmp,
                                                const int* __restrict__ bin_ofs,
                                                uint2* __restrict__ packed,
                                                int* __restrict__ row_start, int N) {
  const int b = blockIdx.x, t = threadIdx.x;
  const int gstart = bin_ofs[b];
  const int M = bin_ofs[b + 1] - gstart;
  __shared__ int cnt[DPB];
  __shared__ int s[DPB];
  __shared__ int cur[DPB];
  __shared__ int ccnt[DPB];
  __shared__ int cofs[DPB + 1];
  __shared__ uint2 data[ECH];  // 32 KB
  cnt[t] = 0;
  __syncthreads();
  for (int i = t; i < M; i += 256) atomicAdd(&cnt[tmp[gstart + i].x >> 16], 1);
  __syncthreads();
  {
    const int own = cnt[t];
    s[t] = own;
    __syncthreads();
    for (int o = 1; o < DPB; o <<= 1) {
      const int a = (t >= o) ? s[t - o] : 0;
      __syncthreads();
      s[t] += a;
      __syncthreads();
    }
    const int ex = s[t] - own;
    cur[t] = gstart + ex;
    const int node = b * DPB + t;
    if (node < N) row_start[node] = gstart + ex;
  }
  __syncthreads();
  for (int cb = 0; cb < M; cb += ECH) {
    const int cc = min(ECH, M - cb);
    ccnt[t] = 0;
    __syncthreads();
    uint2 v[16];
    int dj[16], sj[16];
#pragma unroll
    for (int j = 0; j < 16; ++j) {
      const int li = j * 256 + t;
      dj[j] = -1;
      if (li < cc) {
        v[j] = tmp[gstart + cb + li];
        dj[j] = (int)(v[j].x >> 16);
        sj[j] = atomicAdd(&ccnt[dj[j]], 1);
      }
    }
    __syncthreads();
    const int cown = ccnt[t];
    s[t] = cown;
    __syncthreads();
    for (int o = 1; o < DPB; o <<= 1) {
      const int a = (t >= o) ? s[t - o] : 0;
      __syncthreads();
      s[t] += a;
      __syncthreads();
    }
    cofs[t] = s[t] - cown;
    if (t == 0) cofs[DPB] = cc;
    __syncthreads();
#pragma unroll
    for (int j = 0; j < 16; ++j)
      if (dj[j] >= 0) data[cofs[dj[j]] + sj[j]] = make_uint2(v[j].x & 0xFFFFu, v[j].y);
    __syncthreads();
    for (int i = t; i < cc; i += 256) {
      int lo = 0, hi = DPB;
      while (hi - lo > 1) {
        const int mid = (lo + hi) >> 1;
        if (cofs[mid] <= i) lo = mid; else hi = mid;
      }
      packed[cur[lo] + (i - cofs[lo])] = data[i];
    }
    __syncthreads();
    cur[t] += ccnt[t];
    __syncthreads();
  }
}

// ---------------- K5: single-pass softmax + wide bf16 gather-accum -------
// No max subtraction (softmax is shift-invariant; |alpha| <~ 5, exp safe).
// Gather: 8B ushort4 per lane, half-wave per row -> 4 edges/iteration,
// 4-way cross-slot LDS reduction at the end.
__global__ __launch_bounds__(128) void k5_agg(const unsigned short* __restrict__ xbf,
                                              const uint2* __restrict__ packed,
                                              const int* __restrict__ row_start,
                                              const float* __restrict__ al,
                                              const float* __restrict__ ar,
                                              float* __restrict__ out, int N) {
  const int n = blockIdx.x;
  const int t = threadIdx.x;
  const int s0 = row_start[n];
  const int En = row_start[n + 1] - s0;
  __shared__ float red[128];
  __shared__ float inv8[NH];
  __shared__ float arn[NH];
  __shared__ float ebuf[CHUNK * NH];
  __shared__ float wbuf[CHUNK];
  __shared__ int sbuf[CHUNK];
  __shared__ float sf[4][HC];  // 2 KB: per-residue partial sums
  const int h_a = t & 7, i_a = t >> 3;
  const int wv = t >> 6, l5 = t & 31;
  const int eo = (t >> 5) & 1;     // sub-edge within wave
  const int res4 = wv * 2 + eo;    // residue class 0..3
  const int ch0 = l5 * 4;          // channels ch0..ch0+3
  const int h_g = l5 >> 2;         // head of those channels
  if (t < NH) arn[t] = ar[(size_t)n * NH + t];

  float dpart = 0.f;
  float f0 = 0.f, f1 = 0.f, f2 = 0.f, f3 = 0.f;
  for (int base = 0; base < En; base += CHUNK) {
    const int cnt = min(CHUNK, En - base);
    __syncthreads();
    for (int i = t; i < cnt; i += 128) {
      const uint2 p = packed[s0 + base + i];
      sbuf[i] = (int)p.x;
      wbuf[i] = __uint_as_float(p.y);
    }
    __syncthreads();
    for (int i = i_a; i < cnt; i += 16) {
      float a = wbuf[i] * (al[(size_t)sbuf[i] * NH + h_a] + arn[h_a]);
      a = (a > 0.f) ? a : 0.2f * a;
      const float e = __expf(a);
      ebuf[i * NH + h_a] = e;
      dpart += e;
    }
    __syncthreads();
    for (int i = res4; i < cnt; i += 4) {
      const float e = ebuf[i * NH + h_g];
      const ushort4 xu = *(const ushort4*)(xbf + (size_t)sbuf[i] * HC + ch0);
      f0 = fmaf(e, bf16_to_f(xu.x), f0);
      f1 = fmaf(e, bf16_to_f(xu.y), f1);
      f2 = fmaf(e, bf16_to_f(xu.z), f2);
      f3 = fmaf(e, bf16_to_f(xu.w), f3);
    }
  }
  sf[res4][ch0 + 0] = f0;
  sf[res4][ch0 + 1] = f1;
  sf[res4][ch0 + 2] = f2;
  sf[res4][ch0 + 3] = f3;
  red[t] = dpart;
  __syncthreads();
  if (t < NH) {
    float sden = 0.f;
    for (int j = 0; j < 16; ++j) sden += red[j * NH + t];
    inv8[t] = 1.f / sden;
  }
  __syncthreads();

  const float tot = sf[0][t] + sf[1][t] + sf[2][t] + sf[3][t];
  const float feat = (En > 0) ? tot * inv8[t >> 4] : 0.f;
  const float o = (feat > 0.f) ? feat : (__expf(feat) - 1.f);  // elu
  out[(size_t)n * HC + t] += o;  // out already holds the residual from k1
}

extern "C" void kernel_launch(void* const* d_in, const int* in_sizes, int n_in,
                              void* d_out, int out_size, void* d_ws, size_t ws_size,
                              hipStream_t stream) {
  const float* feature = (const float*)d_in[0];
  const int* esrc = (const int*)d_in[1];
  const int* edst = (const int*)d_in[2];
  const float* ew = (const float*)d_in[3];
  const float* w_lin = (const float*)d_in[4];
  const float* att_l = (const float*)d_in[5];
  const float* att_r = (const float*)d_in[6];
  const float* w_res = (const float*)d_in[7];
  float* out = (float*)d_out;

  const int N = in_sizes[0] / IN_DIM;
  const int E = in_sizes[1];
  const int NB = (N + DPB - 1) / DPB;
  const int nch = (E + ECH - 1) / ECH;

  char* ws = (char*)d_ws;
  size_t off = 0;
  auto alloc = [&](size_t bytes) {
    void* p = ws + off;
    off = (off + bytes + 255) & ~(size_t)255;
    return p;
  };
  unsigned short* xbf = (unsigned short*)alloc((size_t)N * HC * sizeof(unsigned short));
  float* al = (float*)alloc((size_t)N * NH * sizeof(float));
  float* ar = (float*)alloc((size_t)N * NH * sizeof(float));
  int* row_start = (int*)alloc((size_t)(N + 1) * sizeof(int));
  int* bin_count = (int*)alloc((size_t)NBMAX * sizeof(int));
  int* bin_ofs = (int*)alloc((size_t)(NBMAX + 1) * sizeof(int));
  int* bin_cursor = (int*)alloc((size_t)NBMAX * sizeof(int));
  uint2* tmp = (uint2*)alloc((size_t)E * sizeof(uint2));
  uint2* packed = (uint2*)alloc((size_t)E * sizeof(uint2));

  hipMemsetAsync(bin_count, 0, (size_t)NBMAX * sizeof(int), stream);
  k1_fused<<<512, 256, 0, stream>>>(feature, w_lin, w_res, xbf, out, N);
  k1b_attn<<<(N * NH + 255) / 256, 256, 0, stream>>>(xbf, att_l, att_r, al, ar, N);
  k4a_count<<<nch, 256, 0, stream>>>(edst, bin_count, E);
  k3_bins<<<1, NBMAX, 0, stream>>>(bin_count, bin_ofs, bin_cursor, row_start, N);
  k4b_bin<<<nch, 256, 0, stream>>>(esrc, edst, ew, bin_cursor, tmp, E);
  k4c_sort<<<NB, 256, 0, stream>>>(tmp, bin_ofs, packed, row_start, N);
  k5_agg<<<N, 128, 0, stream>>>(xbf, packed, row_start, al, ar, out, N);
}

// Round 7
// 295.854 us; speedup vs baseline: 1.8979x; 1.0087x over previous
//
#include <hip/hip_runtime.h>
#include <math.h>

#define IN_DIM 128
#define NH 8
#define OC 16
#define HC 128   // NH*OC
#define CHUNK 128  // k5 LDS chunk
#define BSTR 136   // padded bf16 LDS stride (16B-aligned rows)
#define DPB 256    // dst nodes per coarse bin (bin = dst >> 8)
#define NBMAX 256
#define ECH 4096   // edges per chunk in binning kernels

typedef __attribute__((ext_vector_type(8))) short short8;
typedef __attribute__((ext_vector_type(4))) float f32x4;

__device__ __forceinline__ unsigned short bf16_rne(float f) {
  unsigned int u = __builtin_bit_cast(unsigned int, f);
  u += 0x7FFFu + ((u >> 16) & 1u);
  return (unsigned short)(u >> 16);
}
__device__ __forceinline__ float bf16_to_f(unsigned short h) {
  unsigned int u = ((unsigned int)h) << 16;
  return __builtin_bit_cast(float, u);
}

// ---------------- K1: xbf = bf16(feature@w_lin), out = feature@w_res -----
// Fused: feature read ONCE, split-A (Ahi+Alo) shared by both products,
// B = bf16-hi only. LDS 69.6 KB -> 2 blocks/CU.
__global__ __launch_bounds__(256) void k1_fused(const float* __restrict__ feature,
                                                const float* __restrict__ w_lin,
                                                const float* __restrict__ w_res,
                                                unsigned short* __restrict__ xbf,
                                                float* __restrict__ out, int N) {
  __shared__ unsigned short BL[HC * BSTR];  // 34.8 KB  w_lin^T hi
  __shared__ unsigned short BR[HC * BSTR];  // 34.8 KB  w_res^T hi
  const int t = threadIdx.x;
  for (int i = t; i < IN_DIM * HC; i += 256) {
    const int r = i >> 7, c = i & 127;  // W[k=r][col=c]
    BL[c * BSTR + r] = bf16_rne(w_lin[i]);
    BR[c * BSTR + r] = bf16_rne(w_res[i]);
  }
  __syncthreads();

  const int wave = t >> 6, lane = t & 63;
  const int n16 = lane & 15, quad = lane >> 4;
  const int nStrips = (N + 15) >> 4;

  for (int strip = blockIdx.x * 4 + wave; strip < nStrips; strip += gridDim.x * 4) {
    const int row0 = strip * 16;
    const int arow = row0 + n16;
    const float* __restrict__ ap =
        feature + (size_t)((arow < N) ? arow : 0) * IN_DIM + quad * 8;
    short8 ahi[4], alo[4];
#pragma unroll
    for (int ks = 0; ks < 4; ++ks) {
      const float4 f0 = *(const float4*)(ap + ks * 32);
      const float4 f1 = *(const float4*)(ap + ks * 32 + 4);
      const float fv[8] = {f0.x, f0.y, f0.z, f0.w, f1.x, f1.y, f1.z, f1.w};
      short8 h, l;
#pragma unroll
      for (int j = 0; j < 8; ++j) {
        const unsigned short hh = bf16_rne(fv[j]);
        h[j] = (short)hh;
        l[j] = (short)bf16_rne(fv[j] - bf16_to_f(hh));
      }
      ahi[ks] = h;
      alo[ks] = l;
    }
    // ---- product 1: x = f @ w_lin -> bf16 ----
#pragma unroll
    for (int cg = 0; cg < 2; ++cg) {
      f32x4 acc[4] = {{0.f,0.f,0.f,0.f},{0.f,0.f,0.f,0.f},{0.f,0.f,0.f,0.f},{0.f,0.f,0.f,0.f}};
#pragma unroll
      for (int ks = 0; ks < 4; ++ks) {
#pragma unroll
        for (int j = 0; j < 4; ++j) {
          const int boff = ((cg * 4 + j) * 16 + n16) * BSTR + ks * 32 + quad * 8;
          const short8 bh = *(const short8*)&BL[boff];
          acc[j] = __builtin_amdgcn_mfma_f32_16x16x32_bf16(ahi[ks], bh, acc[j], 0, 0, 0);
          acc[j] = __builtin_amdgcn_mfma_f32_16x16x32_bf16(alo[ks], bh, acc[j], 0, 0, 0);
        }
      }
#pragma unroll
      for (int j = 0; j < 4; ++j) {
        const int colo = (cg * 4 + j) * 16 + n16;
#pragma unroll
        for (int r = 0; r < 4; ++r) {
          const int rr = row0 + quad * 4 + r;
          if (rr < N) xbf[(size_t)rr * HC + colo] = bf16_rne(acc[j][r]);
        }
      }
    }
    // ---- product 2: residual = f @ w_res -> fp32 out ----
#pragma unroll
    for (int cg = 0; cg < 2; ++cg) {
      f32x4 acc[4] = {{0.f,0.f,0.f,0.f},{0.f,0.f,0.f,0.f},{0.f,0.f,0.f,0.f},{0.f,0.f,0.f,0.f}};
#pragma unroll
      for (int ks = 0; ks < 4; ++ks) {
#pragma unroll
        for (int j = 0; j < 4; ++j) {
          const int boff = ((cg * 4 + j) * 16 + n16) * BSTR + ks * 32 + quad * 8;
          const short8 bh = *(const short8*)&BR[boff];
          acc[j] = __builtin_amdgcn_mfma_f32_16x16x32_bf16(ahi[ks], bh, acc[j], 0, 0, 0);
          acc[j] = __builtin_amdgcn_mfma_f32_16x16x32_bf16(alo[ks], bh, acc[j], 0, 0, 0);
        }
      }
#pragma unroll
      for (int j = 0; j < 4; ++j) {
        const int colo = (cg * 4 + j) * 16 + n16;
#pragma unroll
        for (int r = 0; r < 4; ++r) {
          const int rr = row0 + quad * 4 + r;
          if (rr < N) out[(size_t)rr * HC + colo] = acc[j][r];
        }
      }
    }
  }
}

// ---------------- K1b: al/ar logits + row-scaled int8 quant of x ---------
// err(int8 row-scaled) <= rowmax/254 ~ 0.02 ABSOLUTE (safe even for En=1
// buckets where coef=1; fp8 would fail there with 6% relative error).
__global__ __launch_bounds__(256) void k1b_attn(const unsigned short* __restrict__ xbf,
                                                const float* __restrict__ att_l,
                                                const float* __restrict__ att_r,
                                                float* __restrict__ al,
                                                float* __restrict__ ar,
                                                char* __restrict__ x8,
                                                float* __restrict__ s, int N) {
  const int idx = blockIdx.x * 256 + threadIdx.x;
  if (idx >= N * NH) return;
  const int h = idx & (NH - 1);
  const int n = idx >> 3;
  const ushort4* xp = (const ushort4*)(xbf + (size_t)idx * OC);
  const float4* lp = (const float4*)(att_l + h * OC);
  const float4* rp = (const float4*)(att_r + h * OC);
  float f[16];
  float sl = 0.f, sr = 0.f, m = 0.f;
#pragma unroll
  for (int q = 0; q < 4; ++q) {
    const ushort4 xu = xp[q];
    const float4 lv = lp[q], rv = rp[q];
    f[q * 4 + 0] = bf16_to_f(xu.x);
    f[q * 4 + 1] = bf16_to_f(xu.y);
    f[q * 4 + 2] = bf16_to_f(xu.z);
    f[q * 4 + 3] = bf16_to_f(xu.w);
    sl += f[q*4+0] * lv.x + f[q*4+1] * lv.y + f[q*4+2] * lv.z + f[q*4+3] * lv.w;
    sr += f[q*4+0] * rv.x + f[q*4+1] * rv.y + f[q*4+2] * rv.z + f[q*4+3] * rv.w;
#pragma unroll
    for (int j = 0; j < 4; ++j) m = fmaxf(m, fabsf(f[q * 4 + j]));
  }
  al[idx] = sl;
  ar[idx] = sr;
  // row max across the 8 head-threads (consecutive lanes, same wave)
  m = fmaxf(m, __shfl_xor(m, 1, 64));
  m = fmaxf(m, __shfl_xor(m, 2, 64));
  m = fmaxf(m, __shfl_xor(m, 4, 64));
  const float inv = (m > 0.f) ? 127.f / m : 0.f;
  int4 pk;
  int* pw = (int*)&pk;
#pragma unroll
  for (int w = 0; w < 4; ++w) {
    int b0 = (int)rintf(f[w * 4 + 0] * inv);
    int b1 = (int)rintf(f[w * 4 + 1] * inv);
    int b2 = (int)rintf(f[w * 4 + 2] * inv);
    int b3 = (int)rintf(f[w * 4 + 3] * inv);
    pw[w] = (b0 & 0xFF) | ((b1 & 0xFF) << 8) | ((b2 & 0xFF) << 16) | ((b3 & 0xFF) << 24);
  }
  *(int4*)(x8 + (size_t)n * HC + h * 16) = pk;
  if (h == 0) s[n] = (m > 0.f) ? m / 127.f : 0.f;
}

// ---------------- K4a: coarse-bin histogram (bin = dst>>8) ---------------
__global__ __launch_bounds__(256) void k4a_count(const int* __restrict__ edst,
                                                 int* __restrict__ bin_count, int E) {
  __shared__ int cnt[NBMAX];
  const int t = threadIdx.x;
  cnt[t] = 0;
  __syncthreads();
  const int base = blockIdx.x * ECH;
#pragma unroll
  for (int j = 0; j < ECH / 256; ++j) {
    const int e = base + j * 256 + t;
    if (e < E) atomicAdd(&cnt[edst[e] >> 8], 1);
  }
  __syncthreads();
  if (cnt[t] > 0) atomicAdd(&bin_count[t], cnt[t]);
}

// ---------------- K3: scan bin counts -> bin_ofs / bin_cursor ------------
__global__ __launch_bounds__(NBMAX) void k3_bins(const int* __restrict__ bin_count,
                                                 int* __restrict__ bin_ofs,
                                                 int* __restrict__ bin_cursor,
                                                 int* __restrict__ row_start, int N) {
  __shared__ int s[NBMAX];
  const int t = threadIdx.x;
  const int own = bin_count[t];
  s[t] = own;
  __syncthreads();
  for (int o = 1; o < NBMAX; o <<= 1) {
    const int a = (t >= o) ? s[t - o] : 0;
    __syncthreads();
    s[t] += a;
    __syncthreads();
  }
  const int ex = s[t] - own;
  bin_ofs[t] = ex;
  bin_cursor[t] = ex;
  if (t == NBMAX - 1) {
    bin_ofs[NBMAX] = s[t];
    row_start[N] = s[t];  // = E
  }
}

// ---------------- K4b: bin-scatter with LDS write-combining --------------
__global__ __launch_bounds__(256) void k4b_bin(const int* __restrict__ esrc,
                                               const int* __restrict__ edst,
                                               const float* __restrict__ ew,
                                               int* __restrict__ bin_cursor,
                                               uint2* __restrict__ tmp, int E) {
  __shared__ int cnt[NBMAX];
  __shared__ int s[NBMAX];
  __shared__ int ofs[NBMAX];
  __shared__ int gbase[NBMAX];
  __shared__ uint2 data[ECH];  // 32 KB
  const int t = threadIdx.x;
  cnt[t] = 0;
  __syncthreads();
  const int base = blockIdx.x * ECH;
  uint2 v[16];
  int bj[16], sj[16];
#pragma unroll
  for (int j = 0; j < 16; ++j) {
    const int e = base + j * 256 + t;
    bj[j] = -1;
    if (e < E) {
      const int d = edst[e];
      v[j] = make_uint2((unsigned)esrc[e] | ((unsigned)(d & (DPB - 1)) << 16),
                        __float_as_uint(ew[e]));
      bj[j] = d >> 8;
      sj[j] = atomicAdd(&cnt[bj[j]], 1);
    }
  }
  __syncthreads();
  const int own = cnt[t];
  s[t] = own;
  __syncthreads();
  for (int o = 1; o < NBMAX; o <<= 1) {
    const int a = (t >= o) ? s[t - o] : 0;
    __syncthreads();
    s[t] += a;
    __syncthreads();
  }
  ofs[t] = s[t] - own;
  if (own > 0) gbase[t] = atomicAdd(&bin_cursor[t], own);
  __syncthreads();
#pragma unroll
  for (int j = 0; j < 16; ++j)
    if (bj[j] >= 0) data[ofs[bj[j]] + sj[j]] = v[j];
  __syncthreads();
  const int cc = (base + ECH <= E) ? ECH : (E - base);
  for (int i = t; i < cc; i += 256) {
    int lo = 0, hi = NBMAX - 1;
    while (hi - lo > 1) {
      const int mid = (lo + hi) >> 1;
      if (ofs[mid] <= i) lo = mid; else hi = mid;
    }
    tmp[gbase[lo] + (i - ofs[lo])] = data[i];
  }
}

// ---------------- K4c: per-bin dst-sort -> final CSR + row_start ---------
__global__ __launch_bounds__(256) void k4c_sort(const uint2* __restrict__ tmp,
                                                const int* __restrict__ bin_ofs,
                                                uint2* __restrict__ packed,
                                                int* __restrict__ row_start, int N) {
  const int b = blockIdx.x, t = threadIdx.x;
  const int gstart = bin_ofs[b];
  const int M = bin_ofs[b + 1] - gstart;
  __shared__ int cnt[DPB];
  __shared__ int s[DPB];
  __shared__ int cur[DPB];
  __shared__ int ccnt[DPB];
  __shared__ int cofs[DPB + 1];
  __shared__ uint2 data[ECH];  // 32 KB
  cnt[t] = 0;
  __syncthreads();
  for (int i = t; i < M; i += 256) atomicAdd(&cnt[tmp[gstart + i].x >> 16], 1);
  __syncthreads();
  {
    const int own = cnt[t];
    s[t] = own;
    __syncthreads();
    for (int o = 1; o < DPB; o <<= 1) {
      const int a = (t >= o) ? s[t - o] : 0;
      __syncthreads();
      s[t] += a;
      __syncthreads();
    }
    const int ex = s[t] - own;
    cur[t] = gstart + ex;
    const int node = b * DPB + t;
    if (node < N) row_start[node] = gstart + ex;
  }
  __syncthreads();
  for (int cb = 0; cb < M; cb += ECH) {
    const int cc = min(ECH, M - cb);
    ccnt[t] = 0;
    __syncthreads();
    uint2 v[16];
    int dj[16], sj[16];
#pragma unroll
    for (int j = 0; j < 16; ++j) {
      const int li = j * 256 + t;
      dj[j] = -1;
      if (li < cc) {
        v[j] = tmp[gstart + cb + li];
        dj[j] = (int)(v[j].x >> 16);
        sj[j] = atomicAdd(&ccnt[dj[j]], 1);
      }
    }
    __syncthreads();
    const int cown = ccnt[t];
    s[t] = cown;
    __syncthreads();
    for (int o = 1; o < DPB; o <<= 1) {
      const int a = (t >= o) ? s[t - o] : 0;
      __syncthreads();
      s[t] += a;
      __syncthreads();
    }
    cofs[t] = s[t] - cown;
    if (t == 0) cofs[DPB] = cc;
    __syncthreads();
#pragma unroll
    for (int j = 0; j < 16; ++j)
      if (dj[j] >= 0) data[cofs[dj[j]] + sj[j]] = make_uint2(v[j].x & 0xFFFFu, v[j].y);
    __syncthreads();
    for (int i = t; i < cc; i += 256) {
      int lo = 0, hi = DPB;
      while (hi - lo > 1) {
        const int mid = (lo + hi) >> 1;
        if (cofs[mid] <= i) lo = mid; else hi = mid;
      }
      packed[cur[lo] + (i - cofs[lo])] = data[i];
    }
    __syncthreads();
    cur[t] += ccnt[t];
    __syncthreads();
  }
}

// ---------------- K5: single-pass softmax + int8 gather-accum ------------
// Gather 128 B/row (uint2/lane, 16 lanes/row -> 8 edges per block-iter).
// e*s_src folded into ebuf at exp time; dequant via (char) extracts.
__global__ __launch_bounds__(128) void k5_agg(const char* __restrict__ x8,
                                              const float* __restrict__ s,
                                              const uint2* __restrict__ packed,
                                              const int* __restrict__ row_start,
                                              const float* __restrict__ al,
                                              const float* __restrict__ ar,
                                              float* __restrict__ out, int N) {
  const int n = blockIdx.x;
  const int t = threadIdx.x;
  const int s0 = row_start[n];
  const int En = row_start[n + 1] - s0;
  __shared__ float red[128];
  __shared__ float inv8[NH];
  __shared__ float arn[NH];
  __shared__ float ebuf[CHUNK * NH];  // e * s_src
  __shared__ float wbuf[CHUNK];
  __shared__ float scbuf[CHUNK];
  __shared__ int sbuf[CHUNK];
  __shared__ float sf[8][HC];  // 4 KB: per-residue partial sums
  const int h_a = t & 7, i_a = t >> 3;
  const int res8 = t >> 4;        // residue class 0..7
  const int lane16 = t & 15;
  const int ch0 = lane16 * 8;     // channels ch0..ch0+7
  const int h_g = lane16 >> 1;    // head of those channels
  if (t < NH) arn[t] = ar[(size_t)n * NH + t];

  float dpart = 0.f;
  float f0 = 0.f, f1 = 0.f, f2 = 0.f, f3 = 0.f;
  float f4 = 0.f, f5 = 0.f, f6 = 0.f, f7 = 0.f;
  for (int base = 0; base < En; base += CHUNK) {
    const int cnt = min(CHUNK, En - base);
    __syncthreads();
    for (int i = t; i < cnt; i += 128) {
      const uint2 p = packed[s0 + base + i];
      sbuf[i] = (int)p.x;
      wbuf[i] = __uint_as_float(p.y);
    }
    __syncthreads();
    for (int i = t; i < cnt; i += 128) scbuf[i] = s[sbuf[i]];
    __syncthreads();
    for (int i = i_a; i < cnt; i += 16) {
      float a = wbuf[i] * (al[(size_t)sbuf[i] * NH + h_a] + arn[h_a]);
      a = (a > 0.f) ? a : 0.2f * a;
      const float e = __expf(a);
      dpart += e;
      ebuf[i * NH + h_a] = e * scbuf[i];
    }
    __syncthreads();
    for (int i = res8; i < cnt; i += 8) {
      const float fac = ebuf[i * NH + h_g];
      const int2 qw = *(const int2*)(x8 + (size_t)sbuf[i] * HC + ch0);
      f0 = fmaf(fac, (float)(char)(qw.x), f0);
      f1 = fmaf(fac, (float)(char)(qw.x >> 8), f1);
      f2 = fmaf(fac, (float)(char)(qw.x >> 16), f2);
      f3 = fmaf(fac, (float)(qw.x >> 24), f3);
      f4 = fmaf(fac, (float)(char)(qw.y), f4);
      f5 = fmaf(fac, (float)(char)(qw.y >> 8), f5);
      f6 = fmaf(fac, (float)(char)(qw.y >> 16), f6);
      f7 = fmaf(fac, (float)(qw.y >> 24), f7);
    }
  }
  sf[res8][ch0 + 0] = f0;
  sf[res8][ch0 + 1] = f1;
  sf[res8][ch0 + 2] = f2;
  sf[res8][ch0 + 3] = f3;
  sf[res8][ch0 + 4] = f4;
  sf[res8][ch0 + 5] = f5;
  sf[res8][ch0 + 6] = f6;
  sf[res8][ch0 + 7] = f7;
  red[t] = dpart;
  __syncthreads();
  if (t < NH) {
    float sden = 0.f;
    for (int j = 0; j < 16; ++j) sden += red[j * NH + t];
    inv8[t] = 1.f / sden;
  }
  __syncthreads();

  float tot = 0.f;
#pragma unroll
  for (int r = 0; r < 8; ++r) tot += sf[r][t];
  const float feat = (En > 0) ? tot * inv8[t >> 4] : 0.f;
  const float o = (feat > 0.f) ? feat : (__expf(feat) - 1.f);  // elu
  out[(size_t)n * HC + t] += o;  // out already holds the residual from k1
}

extern "C" void kernel_launch(void* const* d_in, const int* in_sizes, int n_in,
                              void* d_out, int out_size, void* d_ws, size_t ws_size,
                              hipStream_t stream) {
  const float* feature = (const float*)d_in[0];
  const int* esrc = (const int*)d_in[1];
  const int* edst = (const int*)d_in[2];
  const float* ew = (const float*)d_in[3];
  const float* w_lin = (const float*)d_in[4];
  const float* att_l = (const float*)d_in[5];
  const float* att_r = (const float*)d_in[6];
  const float* w_res = (const float*)d_in[7];
  float* out = (float*)d_out;

  const int N = in_sizes[0] / IN_DIM;
  const int E = in_sizes[1];
  const int NB = (N + DPB - 1) / DPB;
  const int nch = (E + ECH - 1) / ECH;

  char* ws = (char*)d_ws;
  size_t off = 0;
  auto alloc = [&](size_t bytes) {
    void* p = ws + off;
    off = (off + bytes + 255) & ~(size_t)255;
    return p;
  };
  unsigned short* xbf = (unsigned short*)alloc((size_t)N * HC * sizeof(unsigned short));
  char* x8 = (char*)alloc((size_t)N * HC);
  float* sscale = (float*)alloc((size_t)N * sizeof(float));
  float* al = (float*)alloc((size_t)N * NH * sizeof(float));
  float* ar = (float*)alloc((size_t)N * NH * sizeof(float));
  int* row_start = (int*)alloc((size_t)(N + 1) * sizeof(int));
  int* bin_count = (int*)alloc((size_t)NBMAX * sizeof(int));
  int* bin_ofs = (int*)alloc((size_t)(NBMAX + 1) * sizeof(int));
  int* bin_cursor = (int*)alloc((size_t)NBMAX * sizeof(int));
  uint2* tmp = (uint2*)alloc((size_t)E * sizeof(uint2));
  uint2* packed = (uint2*)alloc((size_t)E * sizeof(uint2));

  hipMemsetAsync(bin_count, 0, (size_t)NBMAX * sizeof(int), stream);
  k1_fused<<<512, 256, 0, stream>>>(feature, w_lin, w_res, xbf, out, N);
  k1b_attn<<<(N * NH + 255) / 256, 256, 0, stream>>>(xbf, att_l, att_r, al, ar, x8, sscale, N);
  k4a_count<<<nch, 256, 0, stream>>>(edst, bin_count, E);
  k3_bins<<<1, NBMAX, 0, stream>>>(bin_count, bin_ofs, bin_cursor, row_start, N);
  k4b_bin<<<nch, 256, 0, stream>>>(esrc, edst, ew, bin_cursor, tmp, E);
  k4c_sort<<<NB, 256, 0, stream>>>(tmp, bin_ofs, packed, row_start, N);
  k5_agg<<<N, 128, 0, stream>>>(x8, sscale, packed, row_start, al, ar, out, N);
}

// Round 8
// 260.344 us; speedup vs baseline: 2.1568x; 1.1364x over previous
//
#include <hip/hip_runtime.h>
#include <math.h>

#define IN_DIM 128
#define NH 8
#define OC 16
#define HC 128   // NH*OC
#define BSTR 136   // padded bf16 LDS stride (16B-aligned rows)
#define DPB 256    // dst nodes per coarse bin (bin = dst >> 8)
#define NBMAX 256
#define ECH 4096   // edges per chunk in binning kernels

typedef __attribute__((ext_vector_type(8))) short short8;
typedef __attribute__((ext_vector_type(4))) float f32x4;

__device__ __forceinline__ unsigned short bf16_rne(float f) {
  unsigned int u = __builtin_bit_cast(unsigned int, f);
  u += 0x7FFFu + ((u >> 16) & 1u);
  return (unsigned short)(u >> 16);
}
__device__ __forceinline__ float bf16_to_f(unsigned short h) {
  unsigned int u = ((unsigned int)h) << 16;
  return __builtin_bit_cast(float, u);
}

// ---------------- K1: xbf = bf16(feature@w_lin), out = feature@w_res -----
// Fused: feature read ONCE, split-A (Ahi+Alo) shared by both products,
// B = bf16-hi only. LDS 69.6 KB -> 2 blocks/CU.
__global__ __launch_bounds__(256) void k1_fused(const float* __restrict__ feature,
                                                const float* __restrict__ w_lin,
                                                const float* __restrict__ w_res,
                                                unsigned short* __restrict__ xbf,
                                                float* __restrict__ out, int N) {
  __shared__ unsigned short BL[HC * BSTR];  // 34.8 KB  w_lin^T hi
  __shared__ unsigned short BR[HC * BSTR];  // 34.8 KB  w_res^T hi
  const int t = threadIdx.x;
  for (int i = t; i < IN_DIM * HC; i += 256) {
    const int r = i >> 7, c = i & 127;  // W[k=r][col=c]
    BL[c * BSTR + r] = bf16_rne(w_lin[i]);
    BR[c * BSTR + r] = bf16_rne(w_res[i]);
  }
  __syncthreads();

  const int wave = t >> 6, lane = t & 63;
  const int n16 = lane & 15, quad = lane >> 4;
  const int nStrips = (N + 15) >> 4;

  for (int strip = blockIdx.x * 4 + wave; strip < nStrips; strip += gridDim.x * 4) {
    const int row0 = strip * 16;
    const int arow = row0 + n16;
    const float* __restrict__ ap =
        feature + (size_t)((arow < N) ? arow : 0) * IN_DIM + quad * 8;
    short8 ahi[4], alo[4];
#pragma unroll
    for (int ks = 0; ks < 4; ++ks) {
      const float4 f0 = *(const float4*)(ap + ks * 32);
      const float4 f1 = *(const float4*)(ap + ks * 32 + 4);
      const float fv[8] = {f0.x, f0.y, f0.z, f0.w, f1.x, f1.y, f1.z, f1.w};
      short8 h, l;
#pragma unroll
      for (int j = 0; j < 8; ++j) {
        const unsigned short hh = bf16_rne(fv[j]);
        h[j] = (short)hh;
        l[j] = (short)bf16_rne(fv[j] - bf16_to_f(hh));
      }
      ahi[ks] = h;
      alo[ks] = l;
    }
    // ---- product 1: x = f @ w_lin -> bf16 ----
#pragma unroll
    for (int cg = 0; cg < 2; ++cg) {
      f32x4 acc[4] = {{0.f,0.f,0.f,0.f},{0.f,0.f,0.f,0.f},{0.f,0.f,0.f,0.f},{0.f,0.f,0.f,0.f}};
#pragma unroll
      for (int ks = 0; ks < 4; ++ks) {
#pragma unroll
        for (int j = 0; j < 4; ++j) {
          const int boff = ((cg * 4 + j) * 16 + n16) * BSTR + ks * 32 + quad * 8;
          const short8 bh = *(const short8*)&BL[boff];
          acc[j] = __builtin_amdgcn_mfma_f32_16x16x32_bf16(ahi[ks], bh, acc[j], 0, 0, 0);
          acc[j] = __builtin_amdgcn_mfma_f32_16x16x32_bf16(alo[ks], bh, acc[j], 0, 0, 0);
        }
      }
#pragma unroll
      for (int j = 0; j < 4; ++j) {
        const int colo = (cg * 4 + j) * 16 + n16;
#pragma unroll
        for (int r = 0; r < 4; ++r) {
          const int rr = row0 + quad * 4 + r;
          if (rr < N) xbf[(size_t)rr * HC + colo] = bf16_rne(acc[j][r]);
        }
      }
    }
    // ---- product 2: residual = f @ w_res -> fp32 out ----
#pragma unroll
    for (int cg = 0; cg < 2; ++cg) {
      f32x4 acc[4] = {{0.f,0.f,0.f,0.f},{0.f,0.f,0.f,0.f},{0.f,0.f,0.f,0.f},{0.f,0.f,0.f,0.f}};
#pragma unroll
      for (int ks = 0; ks < 4; ++ks) {
#pragma unroll
        for (int j = 0; j < 4; ++j) {
          const int boff = ((cg * 4 + j) * 16 + n16) * BSTR + ks * 32 + quad * 8;
          const short8 bh = *(const short8*)&BR[boff];
          acc[j] = __builtin_amdgcn_mfma_f32_16x16x32_bf16(ahi[ks], bh, acc[j], 0, 0, 0);
          acc[j] = __builtin_amdgcn_mfma_f32_16x16x32_bf16(alo[ks], bh, acc[j], 0, 0, 0);
        }
      }
#pragma unroll
      for (int j = 0; j < 4; ++j) {
        const int colo = (cg * 4 + j) * 16 + n16;
#pragma unroll
        for (int r = 0; r < 4; ++r) {
          const int rr = row0 + quad * 4 + r;
          if (rr < N) out[(size_t)rr * HC + colo] = acc[j][r];
        }
      }
    }
  }
}

// ---------------- K1b: al/ar logits + row-scaled int8 quant of x ---------
__global__ __launch_bounds__(256) void k1b_attn(const unsigned short* __restrict__ xbf,
                                                const float* __restrict__ att_l,
                                                const float* __restrict__ att_r,
                                                float* __restrict__ al,
                                                float* __restrict__ ar,
                                                char* __restrict__ x8,
                                                float* __restrict__ s, int N) {
  const int idx = blockIdx.x * 256 + threadIdx.x;
  if (idx >= N * NH) return;
  const int h = idx & (NH - 1);
  const int n = idx >> 3;
  const ushort4* xp = (const ushort4*)(xbf + (size_t)idx * OC);
  const float4* lp = (const float4*)(att_l + h * OC);
  const float4* rp = (const float4*)(att_r + h * OC);
  float f[16];
  float sl = 0.f, sr = 0.f, m = 0.f;
#pragma unroll
  for (int q = 0; q < 4; ++q) {
    const ushort4 xu = xp[q];
    const float4 lv = lp[q], rv = rp[q];
    f[q * 4 + 0] = bf16_to_f(xu.x);
    f[q * 4 + 1] = bf16_to_f(xu.y);
    f[q * 4 + 2] = bf16_to_f(xu.z);
    f[q * 4 + 3] = bf16_to_f(xu.w);
    sl += f[q*4+0] * lv.x + f[q*4+1] * lv.y + f[q*4+2] * lv.z + f[q*4+3] * lv.w;
    sr += f[q*4+0] * rv.x + f[q*4+1] * rv.y + f[q*4+2] * rv.z + f[q*4+3] * rv.w;
#pragma unroll
    for (int j = 0; j < 4; ++j) m = fmaxf(m, fabsf(f[q * 4 + j]));
  }
  al[idx] = sl;
  ar[idx] = sr;
  m = fmaxf(m, __shfl_xor(m, 1, 64));
  m = fmaxf(m, __shfl_xor(m, 2, 64));
  m = fmaxf(m, __shfl_xor(m, 4, 64));
  const float inv = (m > 0.f) ? 127.f / m : 0.f;
  int4 pk;
  int* pw = (int*)&pk;
#pragma unroll
  for (int w = 0; w < 4; ++w) {
    int b0 = (int)rintf(f[w * 4 + 0] * inv);
    int b1 = (int)rintf(f[w * 4 + 1] * inv);
    int b2 = (int)rintf(f[w * 4 + 2] * inv);
    int b3 = (int)rintf(f[w * 4 + 3] * inv);
    pw[w] = (b0 & 0xFF) | ((b1 & 0xFF) << 8) | ((b2 & 0xFF) << 16) | ((b3 & 0xFF) << 24);
  }
  *(int4*)(x8 + (size_t)n * HC + h * 16) = pk;
  if (h == 0) s[n] = (m > 0.f) ? m / 127.f : 0.f;
}

// ---------------- K4a: coarse-bin histogram (bin = dst>>8) ---------------
__global__ __launch_bounds__(256) void k4a_count(const int* __restrict__ edst,
                                                 int* __restrict__ bin_count, int E) {
  __shared__ int cnt[NBMAX];
  const int t = threadIdx.x;
  cnt[t] = 0;
  __syncthreads();
  const int base = blockIdx.x * ECH;
#pragma unroll
  for (int j = 0; j < ECH / 256; ++j) {
    const int e = base + j * 256 + t;
    if (e < E) atomicAdd(&cnt[edst[e] >> 8], 1);
  }
  __syncthreads();
  if (cnt[t] > 0) atomicAdd(&bin_count[t], cnt[t]);
}

// ---------------- K3: scan bin counts -> bin_ofs / bin_cursor ------------
__global__ __launch_bounds__(NBMAX) void k3_bins(const int* __restrict__ bin_count,
                                                 int* __restrict__ bin_ofs,
                                                 int* __restrict__ bin_cursor,
                                                 int* __restrict__ row_start, int N) {
  __shared__ int s[NBMAX];
  const int t = threadIdx.x;
  const int own = bin_count[t];
  s[t] = own;
  __syncthreads();
  for (int o = 1; o < NBMAX; o <<= 1) {
    const int a = (t >= o) ? s[t - o] : 0;
    __syncthreads();
    s[t] += a;
    __syncthreads();
  }
  const int ex = s[t] - own;
  bin_ofs[t] = ex;
  bin_cursor[t] = ex;
  if (t == NBMAX - 1) {
    bin_ofs[NBMAX] = s[t];
    row_start[N] = s[t];  // = E
  }
}

// ---------------- K4b: bin-scatter with LDS write-combining --------------
__global__ __launch_bounds__(256) void k4b_bin(const int* __restrict__ esrc,
                                               const int* __restrict__ edst,
                                               const float* __restrict__ ew,
                                               int* __restrict__ bin_cursor,
                                               uint2* __restrict__ tmp, int E) {
  __shared__ int cnt[NBMAX];
  __shared__ int s[NBMAX];
  __shared__ int ofs[NBMAX];
  __shared__ int gbase[NBMAX];
  __shared__ uint2 data[ECH];  // 32 KB
  const int t = threadIdx.x;
  cnt[t] = 0;
  __syncthreads();
  const int base = blockIdx.x * ECH;
  uint2 v[16];
  int bj[16], sj[16];
#pragma unroll
  for (int j = 0; j < 16; ++j) {
    const int e = base + j * 256 + t;
    bj[j] = -1;
    if (e < E) {
      const int d = edst[e];
      v[j] = make_uint2((unsigned)esrc[e] | ((unsigned)(d & (DPB - 1)) << 16),
                        __float_as_uint(ew[e]));
      bj[j] = d >> 8;
      sj[j] = atomicAdd(&cnt[bj[j]], 1);
    }
  }
  __syncthreads();
  const int own = cnt[t];
  s[t] = own;
  __syncthreads();
  for (int o = 1; o < NBMAX; o <<= 1) {
    const int a = (t >= o) ? s[t - o] : 0;
    __syncthreads();
    s[t] += a;
    __syncthreads();
  }
  ofs[t] = s[t] - own;
  if (own > 0) gbase[t] = atomicAdd(&bin_cursor[t], own);
  __syncthreads();
#pragma unroll
  for (int j = 0; j < 16; ++j)
    if (bj[j] >= 0) data[ofs[bj[j]] + sj[j]] = v[j];
  __syncthreads();
  const int cc = (base + ECH <= E) ? ECH : (E - base);
  for (int i = t; i < cc; i += 256) {
    int lo = 0, hi = NBMAX - 1;
    while (hi - lo > 1) {
      const int mid = (lo + hi) >> 1;
      if (ofs[mid] <= i) lo = mid; else hi = mid;
    }
    tmp[gbase[lo] + (i - ofs[lo])] = data[i];
  }
}

// ---------------- K4c: per-bin dst-sort -> final CSR + row_start ---------
__global__ __launch_bounds__(256) void k4c_sort(const uint2* __restrict__ tmp,
                                                const int* __restrict__ bin_ofs,
                                                uint2* __restrict__ packed,
                                                int* __restrict__ row_start, int N) {
  const int b = blockIdx.x, t = threadIdx.x;
  const int gstart = bin_ofs[b];
  const int M = bin_ofs[b + 1] - gstart;
  __shared__ int cnt[DPB];
  __shared__ int s[DPB];
  __shared__ int cur[DPB];
  __shared__ int ccnt[DPB];
  __shared__ int cofs[DPB + 1];
  __shared__ uint2 data[ECH];  // 32 KB
  cnt[t] = 0;
  __syncthreads();
  for (int i = t; i < M; i += 256) atomicAdd(&cnt[tmp[gstart + i].x >> 16], 1);
  __syncthreads();
  {
    const int own = cnt[t];
    s[t] = own;
    __syncthreads();
    for (int o = 1; o < DPB; o <<= 1) {
      const int a = (t >= o) ? s[t - o] : 0;
      __syncthreads();
      s[t] += a;
      __syncthreads();
    }
    const int ex = s[t] - own;
    cur[t] = gstart + ex;
    const int node = b * DPB + t;
    if (node < N) row_start[node] = gstart + ex;
  }
  __syncthreads();
  for (int cb = 0; cb < M; cb += ECH) {
    const int cc = min(ECH, M - cb);
    ccnt[t] = 0;
    __syncthreads();
    uint2 v[16];
    int dj[16], sj[16];
#pragma unroll
    for (int j = 0; j < 16; ++j) {
      const int li = j * 256 + t;
      dj[j] = -1;
      if (li < cc) {
        v[j] = tmp[gstart + cb + li];
        dj[j] = (int)(v[j].x >> 16);
        sj[j] = atomicAdd(&ccnt[dj[j]], 1);
      }
    }
    __syncthreads();
    const int cown = ccnt[t];
    s[t] = cown;
    __syncthreads();
    for (int o = 1; o < DPB; o <<= 1) {
      const int a = (t >= o) ? s[t - o] : 0;
      __syncthreads();
      s[t] += a;
      __syncthreads();
    }
    cofs[t] = s[t] - cown;
    if (t == 0) cofs[DPB] = cc;
    __syncthreads();
#pragma unroll
    for (int j = 0; j < 16; ++j)
      if (dj[j] >= 0) data[cofs[dj[j]] + sj[j]] = make_uint2(v[j].x & 0xFFFFu, v[j].y);
    __syncthreads();
    for (int i = t; i < cc; i += 256) {
      int lo = 0, hi = DPB;
      while (hi - lo > 1) {
        const int mid = (lo + hi) >> 1;
        if (cofs[mid] <= i) lo = mid; else hi = mid;
      }
      packed[cur[lo] + (i - cofs[lo])] = data[i];
    }
    __syncthreads();
    cur[t] += ccnt[t];
    __syncthreads();
  }
}

// ---------------- K5: ONE WAVE PER NODE, barrier-free fused loop ---------
// lane = g*8+h: head h owns channels h*16..h*16+15 (head of ch == h), edge
// residue g. exp lane == gather lane -> e stays in registers, no ebuf.
// Single-wave workgroup: __syncthreads compiles to waitcnt only (s_barrier
// elided). LDS = 768 B broadcast-staging, conflict-free.
__global__ __launch_bounds__(64) void k5_agg(const char* __restrict__ x8,
                                             const float* __restrict__ s,
                                             const uint2* __restrict__ packed,
                                             const int* __restrict__ row_start,
                                             const float* __restrict__ al,
                                             const float* __restrict__ ar,
                                             float* __restrict__ out, int N) {
  const int n = blockIdx.x;
  const int l = threadIdx.x;
  const int s0 = row_start[n];
  const int En = row_start[n + 1] - s0;
  if (En == 0) return;  // out already holds residual; elu(0)=0
  __shared__ int sbuf[64];
  __shared__ float wbuf[64];
  __shared__ float scbuf[64];
  const int h = l & 7;   // my head == head of my channel block
  const int g = l >> 3;  // my edge residue
  const int ch0 = h * 16;

  const float arn = ar[(size_t)n * NH + h];
  float dpart = 0.f;
  float f[16];
#pragma unroll
  for (int j = 0; j < 16; ++j) f[j] = 0.f;

  for (int base = 0; base < En; base += 64) {
    const int cnt = min(64, En - base);
    __syncthreads();  // waitcnt only: protect staging reuse
    if (l < cnt) {
      const uint2 p = packed[s0 + base + l];
      const int src = (int)p.x;
      sbuf[l] = src;
      wbuf[l] = __uint_as_float(p.y);
      scbuf[l] = s[src];
    }
    __syncthreads();  // waitcnt only
    for (int i = g; i < cnt; i += 8) {
      const int src = sbuf[i];
      float a = wbuf[i] * (al[(size_t)src * NH + h] + arn);
      a = (a > 0.f) ? a : 0.2f * a;
      const float e = __expf(a);
      dpart += e;
      const float fac = e * scbuf[i];
      const int4 qw = *(const int4*)(x8 + (size_t)src * HC + ch0);
      f[0]  = fmaf(fac, (float)(char)(qw.x),        f[0]);
      f[1]  = fmaf(fac, (float)(char)(qw.x >> 8),   f[1]);
      f[2]  = fmaf(fac, (float)(char)(qw.x >> 16),  f[2]);
      f[3]  = fmaf(fac, (float)(qw.x >> 24),        f[3]);
      f[4]  = fmaf(fac, (float)(char)(qw.y),        f[4]);
      f[5]  = fmaf(fac, (float)(char)(qw.y >> 8),   f[5]);
      f[6]  = fmaf(fac, (float)(char)(qw.y >> 16),  f[6]);
      f[7]  = fmaf(fac, (float)(qw.y >> 24),        f[7]);
      f[8]  = fmaf(fac, (float)(char)(qw.z),        f[8]);
      f[9]  = fmaf(fac, (float)(char)(qw.z >> 8),   f[9]);
      f[10] = fmaf(fac, (float)(char)(qw.z >> 16),  f[10]);
      f[11] = fmaf(fac, (float)(qw.z >> 24),        f[11]);
      f[12] = fmaf(fac, (float)(char)(qw.w),        f[12]);
      f[13] = fmaf(fac, (float)(char)(qw.w >> 8),   f[13]);
      f[14] = fmaf(fac, (float)(char)(qw.w >> 16),  f[14]);
      f[15] = fmaf(fac, (float)(qw.w >> 24),        f[15]);
    }
  }
  // denom: reduce over the 8 edge-residue groups (same head class)
  dpart += __shfl_xor(dpart, 8);
  dpart += __shfl_xor(dpart, 16);
  dpart += __shfl_xor(dpart, 32);
  const float inv = 1.f / dpart;  // for head h == my channels' head
  // channels: reduce over the 8 residue groups
#pragma unroll
  for (int j = 0; j < 16; ++j) {
    f[j] += __shfl_xor(f[j], 8);
    f[j] += __shfl_xor(f[j], 16);
    f[j] += __shfl_xor(f[j], 32);
  }
  if (g == 0) {  // lanes 0..7 write 16 channels each
    float* __restrict__ outp = out + (size_t)n * HC + ch0;
#pragma unroll
    for (int j = 0; j < 16; ++j) {
      const float feat = f[j] * inv;
      const float o = (feat > 0.f) ? feat : (__expf(feat) - 1.f);  // elu
      outp[j] += o;  // out already holds the residual from k1
    }
  }
}

extern "C" void kernel_launch(void* const* d_in, const int* in_sizes, int n_in,
                              void* d_out, int out_size, void* d_ws, size_t ws_size,
                              hipStream_t stream) {
  const float* feature = (const float*)d_in[0];
  const int* esrc = (const int*)d_in[1];
  const int* edst = (const int*)d_in[2];
  const float* ew = (const float*)d_in[3];
  const float* w_lin = (const float*)d_in[4];
  const float* att_l = (const float*)d_in[5];
  const float* att_r = (const float*)d_in[6];
  const float* w_res = (const float*)d_in[7];
  float* out = (float*)d_out;

  const int N = in_sizes[0] / IN_DIM;
  const int E = in_sizes[1];
  const int NB = (N + DPB - 1) / DPB;
  const int nch = (E + ECH - 1) / ECH;

  char* ws = (char*)d_ws;
  size_t off = 0;
  auto alloc = [&](size_t bytes) {
    void* p = ws + off;
    off = (off + bytes + 255) & ~(size_t)255;
    return p;
  };
  unsigned short* xbf = (unsigned short*)alloc((size_t)N * HC * sizeof(unsigned short));
  char* x8 = (char*)alloc((size_t)N * HC);
  float* sscale = (float*)alloc((size_t)N * sizeof(float));
  float* al = (float*)alloc((size_t)N * NH * sizeof(float));
  float* ar = (float*)alloc((size_t)N * NH * sizeof(float));
  int* row_start = (int*)alloc((size_t)(N + 1) * sizeof(int));
  int* bin_count = (int*)alloc((size_t)NBMAX * sizeof(int));
  int* bin_ofs = (int*)alloc((size_t)(NBMAX + 1) * sizeof(int));
  int* bin_cursor = (int*)alloc((size_t)NBMAX * sizeof(int));
  uint2* tmp = (uint2*)alloc((size_t)E * sizeof(uint2));
  uint2* packed = (uint2*)alloc((size_t)E * sizeof(uint2));

  hipMemsetAsync(bin_count, 0, (size_t)NBMAX * sizeof(int), stream);
  k1_fused<<<512, 256, 0, stream>>>(feature, w_lin, w_res, xbf, out, N);
  k1b_attn<<<(N * NH + 255) / 256, 256, 0, stream>>>(xbf, att_l, att_r, al, ar, x8, sscale, N);
  k4a_count<<<nch, 256, 0, stream>>>(edst, bin_count, E);
  k3_bins<<<1, NBMAX, 0, stream>>>(bin_count, bin_ofs, bin_cursor, row_start, N);
  k4b_bin<<<nch, 256, 0, stream>>>(esrc, edst, ew, bin_cursor, tmp, E);
  k4c_sort<<<NB, 256, 0, stream>>>(tmp, bin_ofs, packed, row_start, N);
  k5_agg<<<N, 64, 0, stream>>>(x8, sscale, packed, row_start, al, ar, out, N);
}